// Round 2
// baseline (479.137 us; speedup 1.0000x reference)
//
#include <hip/hip_runtime.h>

typedef __bf16 bf16x8 __attribute__((ext_vector_type(8)));
typedef float  f32x4  __attribute__((ext_vector_type(4)));

#define DEVI static __device__ __forceinline__

DEVI unsigned short f2bf(float f) {
  union { float f; unsigned u; } v; v.f = f;
  unsigned u = v.u;
  u += 0x7fffu + ((u >> 16) & 1u);
  return (unsigned short)(u >> 16);
}
DEVI float bf2f(unsigned short s) {
  union { unsigned u; float f; } v; v.u = ((unsigned)s) << 16;
  return v.f;
}

// ---------------- prep: weights -> bf16, rel-pos bias expand, Wqkv rowsums ----
__global__ void prep_kernel(const float* __restrict__ Wqkv, const float* __restrict__ Wproj,
                            const float* __restrict__ table,
                            unsigned short* __restrict__ wq, unsigned short* __restrict__ wp,
                            float* __restrict__ biasg, float* __restrict__ rowsum) {
  const int i = blockIdx.x * 256 + threadIdx.x;
  if (i < 768 * 256) wq[i] = f2bf(Wqkv[i]);
  if (i < 256 * 256) wp[i] = f2bf(Wproj[i]);
  if (i < 8 * 64 * 64) {
    const int h = i >> 12, r = (i >> 6) & 63, c = i & 63;
    const int ridx = ((r >> 3) - (c >> 3) + 7) * 15 + ((r & 7) - (c & 7) + 7);
    biasg[i] = table[ridx * 8 + h];
  }
  if (i < 768) {
    const float4* p = reinterpret_cast<const float4*>(Wqkv + (size_t)i * 256);
    float s = 0.f;
#pragma unroll
    for (int j = 0; j < 64; ++j) { const float4 a = p[j]; s += a.x + a.y + a.z + a.w; }
    rowsum[i] = s;
  }
}

// LDS layout (bytes):
//  XN @ 0      : 64 rows x 512B  xhat bf16 [l][c], chunk-XOR swizzled; alive ph1->ph5
//  ST @ 32768  : 256 x {mean, sigma} f32 (2048B)
//  Q  @ 34816  : [8][64][80B] q bf16 [h][l][d] (80B padded rows); ao overlays in ph4
//  K  @ 75776  : [8][64][80B]; per-wave P (64x128B swizzled) overlays K[2w..2w+1] in ph4
//  V  @ 116736 : [8][32][128B] v bf16 [h][d][m'], chunk-XOR swizzled rows
//  XW @ 34816  : raw window f32 [cc][r] rows 272B (overlays Q/K; dead after ph1)
#define LDS_XN 0u
#define LDS_ST 32768u
#define LDS_Q  34816u
#define LDS_K  75776u
#define LDS_V  116736u
#define LDS_XW 34816u
#define LDS_TOTAL 149504u

__global__ void __launch_bounds__(256, 1)
win_attn_kernel(const float* __restrict__ X,
                const float* __restrict__ preg, const float* __restrict__ preb,
                const float* __restrict__ postg, const float* __restrict__ postb,
                const float* __restrict__ bqkv, const float* __restrict__ bproj,
                const unsigned short* __restrict__ wq, const unsigned short* __restrict__ wp,
                const float* __restrict__ biasg, const float* __restrict__ rowsum,
                float* __restrict__ out) {
  __shared__ alignas(16) unsigned char sh[LDS_TOTAL];
  const int tid = threadIdx.x;
  const int w = tid >> 6;
  const int lane = tid & 63, lm = lane & 15, lg = lane >> 4;
  // XCD-pairing swizzle: windows b and b^1 share X cache lines -> same XCD chunk
  const int orig = blockIdx.x;
  const int b = (orig & 7) * 256 + (orig >> 3);
  const int n = b >> 8, gh = (b >> 4) & 15, gw = b & 15;
  const size_t wbase = (size_t)n * 4194304 + (size_t)gh * 1024 + (size_t)gw * 8;

  // ---------- phase 0: coalesced stage of raw window -> XW[cc][r] f32 ----------
  {
#pragma unroll
    for (int i = 0; i < 8; ++i) {
      const int rid = i * 256 + tid;
      const int cc = rid >> 3, w0 = rid & 7;
      const float* xb = X + wbase + (size_t)cc * 16384 + w0 * 128;
      const float4 a  = *reinterpret_cast<const float4*>(xb);
      const float4 bv = *reinterpret_cast<const float4*>(xb + 4);
      const unsigned xorv = (cc & 64) ? 16u : 0u;   // r-bit2 XOR cc-bit6 (bank spread)
      unsigned char* dst = sh + LDS_XW + (unsigned)cc * 272u + (unsigned)w0 * 32u;
      *reinterpret_cast<float4*>(dst + xorv)         = a;
      *reinterpret_cast<float4*>(dst + (16u ^ xorv)) = bv;
    }
  }
  __syncthreads();

  // ---------- phase 1: pre-LN per attn-channel c; write xhat -> XN, stats -> ST --
  // xp[c][l] = X[n][(c&3)*64+l][gh*8 + (c>>5)][gw*8 + ((c>>2)&7)]  (the reshape scramble)
  {
    const int c = tid;
    const int r = ((c >> 5) << 3) + ((c >> 2) & 7);
    const unsigned base = LDS_XW + (unsigned)(c & 3) * (64u * 272u)
                        + 4u * (unsigned)(r ^ ((c & 1) << 2));
    float fv[64];
    float s1 = 0.f, s2 = 0.f;
#pragma unroll
    for (int l = 0; l < 64; ++l) {
      const float v = *reinterpret_cast<const float*>(sh + base + (unsigned)l * 272u);
      fv[l] = v; s1 += v; s2 += v * v;
    }
    const float mean = s1 * (1.f / 64.f);
    float var = s2 * (1.f / 64.f) - mean * mean;
    var = fmaxf(var, 0.f) + 1e-5f;
    const float rstd = rsqrtf(var);
    const float sig  = var * rstd;      // sqrt(var+eps) = 1/rstd
#pragma unroll
    for (int l = 0; l < 64; ++l) {
      *(unsigned short*)(sh + LDS_XN + l * 512 +
          (((unsigned)(2 * c)) ^ ((unsigned)((l & 7) << 4)))) = f2bf((fv[l] - mean) * rstd);
    }
    *reinterpret_cast<float2*>(sh + LDS_ST + c * 8) = float2{mean, sig};
  }
  __syncthreads();

  // ---------- phase 2: QKV GEMM on xhat (affine folded), route q/k/v ----------
  {
    float pg4[4], pb4[4];
#pragma unroll
    for (int nt = 0; nt < 4; ++nt) { pg4[nt] = preg[nt * 16 + lm]; pb4[nt] = preb[nt * 16 + lm]; }
#pragma unroll 1
    for (int mc = 0; mc < 3; ++mc) {
      const int obase = w * 192 + mc * 64;
      f32x4 acc[4][4];
#pragma unroll
      for (int i = 0; i < 4; ++i)
#pragma unroll
        for (int j = 0; j < 4; ++j) acc[i][j] = f32x4{0.f, 0.f, 0.f, 0.f};
      for (int ks = 0; ks < 8; ++ks) {
        bf16x8 bfrag[4];
#pragma unroll
        for (int nt = 0; nt < 4; ++nt) {
          const int l = nt * 16 + lm;
          bfrag[nt] = *reinterpret_cast<const bf16x8*>(
              sh + LDS_XN + l * 512 + (((unsigned)(ks * 64 + lg * 16)) ^ ((unsigned)((l & 7) << 4))));
        }
#pragma unroll
        for (int m4 = 0; m4 < 4; ++m4) {
          const int o = obase + m4 * 16 + lm;
          const bf16x8 a = *reinterpret_cast<const bf16x8*>(
              (const unsigned char*)wq + ((size_t)o * 512 + ks * 64 + lg * 16));
#pragma unroll
          for (int nt = 0; nt < 4; ++nt)
            acc[m4][nt] = __builtin_amdgcn_mfma_f32_16x16x32_bf16(a, bfrag[nt], acc[m4][nt], 0, 0, 0);
        }
      }
#pragma unroll
      for (int m4 = 0; m4 < 4; ++m4) {
        const int ob = obase + m4 * 16;
#pragma unroll
        for (int reg = 0; reg < 4; ++reg) {
          const int o = ob + lg * 4 + reg;
          const float rs = rowsum[o];
          const float bq = bqkv[o];
#pragma unroll
          for (int nt = 0; nt < 4; ++nt) {
            const int l = nt * 16 + lm;
            const float val = pg4[nt] * acc[m4][nt][reg] + pb4[nt] * rs + bq;
            if (ob < 256) {
              const int h = o >> 5, d = o & 31;
              *(unsigned short*)(sh + LDS_Q + h * 5120 + l * 80 + 2 * d) = f2bf(val);
            } else if (ob < 512) {
              const int o2 = o - 256; const int h = o2 >> 5, d = o2 & 31;
              *(unsigned short*)(sh + LDS_K + h * 5120 + l * 80 + 2 * d) = f2bf(val);
            } else {
              const int o2 = o - 512; const int h = o2 >> 5, d = o2 & 31;
              *(unsigned short*)(sh + LDS_V + h * 4096 + d * 128 +
                  (((unsigned)(2 * l)) ^ ((unsigned)((d & 7) << 4)))) = f2bf(val);
            }
          }
        }
      }
    }
  }
  __syncthreads();

  // ---------- phase 3: L2-normalize q and k rows ----------
  {
#pragma unroll
    for (int j = 0; j < 4; ++j) {
      const int rr = tid + 256 * j;
      const unsigned base = (rr < 512) ? LDS_Q : LDS_K;
      const int q = rr & 511;
      const int h = q >> 6, l = q & 63;
      unsigned* row = (unsigned*)(sh + base + h * 5120 + l * 80);
      unsigned u[16];
      float ss = 0.f;
#pragma unroll
      for (int t2 = 0; t2 < 16; ++t2) {
        u[t2] = row[t2];
        const float lo = bf2f((unsigned short)(u[t2] & 0xffffu));
        const float hi = bf2f((unsigned short)(u[t2] >> 16));
        ss += lo * lo + hi * hi;
      }
      const float inv = 1.f / fmaxf(sqrtf(ss), 1e-12f);
#pragma unroll
      for (int t2 = 0; t2 < 16; ++t2) {
        const float lo = bf2f((unsigned short)(u[t2] & 0xffffu)) * inv;
        const float hi = bf2f((unsigned short)(u[t2] >> 16)) * inv;
        row[t2] = (unsigned)f2bf(lo) | (((unsigned)f2bf(hi)) << 16);
      }
    }
  }
  __syncthreads();

  // ---------- phase 4: attention, wave w -> heads 2w, 2w+1; P overlays own K rows --
  {
    const unsigned pbase = LDS_K + (unsigned)w * 10240u;
    bf16x8 kf[2][4];
#pragma unroll
    for (int hp = 0; hp < 2; ++hp)
#pragma unroll
      for (int nt = 0; nt < 4; ++nt)
        kf[hp][nt] = *reinterpret_cast<const bf16x8*>(
            sh + LDS_K + (2 * w + hp) * 5120 + (nt * 16 + lm) * 80 + lg * 16);
    asm volatile("s_waitcnt lgkmcnt(0)" ::: "memory");
#pragma unroll 1
    for (int hp = 0; hp < 2; ++hp) {
      const int h = 2 * w + hp;
      bf16x8 qf[4];
#pragma unroll
      for (int mt = 0; mt < 4; ++mt)
        qf[mt] = *reinterpret_cast<const bf16x8*>(sh + LDS_Q + h * 5120 + (mt * 16 + lm) * 80 + lg * 16);
      f32x4 s[4][4];
#pragma unroll
      for (int nt = 0; nt < 4; ++nt)
#pragma unroll
        for (int mt = 0; mt < 4; ++mt)
          s[mt][nt] = __builtin_amdgcn_mfma_f32_16x16x32_bf16(qf[mt], kf[hp][nt], f32x4{0.f,0.f,0.f,0.f}, 0, 0, 0);
      const float* bh = biasg + h * 4096;
      float p[4][4][4];
      float rinv[4][4];
#pragma unroll
      for (int mt = 0; mt < 4; ++mt)
#pragma unroll
        for (int reg = 0; reg < 4; ++reg) {
          const int rrow = mt * 16 + lg * 4 + reg;
          float m = -1e30f;
#pragma unroll
          for (int nt = 0; nt < 4; ++nt) {
            const float v = s[mt][nt][reg] + bh[rrow * 64 + nt * 16 + lm];
            p[mt][nt][reg] = v;
            m = fmaxf(m, v);
          }
          m = fmaxf(m, __shfl_xor(m, 1));
          m = fmaxf(m, __shfl_xor(m, 2));
          m = fmaxf(m, __shfl_xor(m, 4));
          m = fmaxf(m, __shfl_xor(m, 8));
          float sum = 0.f;
#pragma unroll
          for (int nt = 0; nt < 4; ++nt) {
            const float e = __expf(p[mt][nt][reg] - m);
            p[mt][nt][reg] = e;
            sum += e;
          }
          sum += __shfl_xor(sum, 1);
          sum += __shfl_xor(sum, 2);
          sum += __shfl_xor(sum, 4);
          sum += __shfl_xor(sum, 8);
          rinv[mt][reg] = 1.f / sum;
        }
#pragma unroll
      for (int mt = 0; mt < 4; ++mt)
#pragma unroll
        for (int reg = 0; reg < 4; ++reg) {
          const int rrow = mt * 16 + lg * 4 + reg;
#pragma unroll
          for (int nt = 0; nt < 4; ++nt) {
            const int ccol = nt * 16 + lm;
            *(unsigned short*)(sh + pbase + rrow * 128 +
                (((unsigned)(2 * ccol)) ^ ((unsigned)((rrow & 7) << 4)))) = f2bf(p[mt][nt][reg] * rinv[mt][reg]);
          }
        }
      f32x4 oacc[4][2];
#pragma unroll
      for (int mt = 0; mt < 4; ++mt) { oacc[mt][0] = f32x4{0.f,0.f,0.f,0.f}; oacc[mt][1] = f32x4{0.f,0.f,0.f,0.f}; }
#pragma unroll
      for (int ks = 0; ks < 2; ++ks) {
        bf16x8 pa[4];
#pragma unroll
        for (int mt = 0; mt < 4; ++mt) {
          const int l = mt * 16 + lm;
          pa[mt] = *reinterpret_cast<const bf16x8*>(
              sh + pbase + l * 128 + (((unsigned)(ks * 64 + lg * 16)) ^ ((unsigned)((l & 7) << 4))));
        }
#pragma unroll
        for (int nt = 0; nt < 2; ++nt) {
          const int d = nt * 16 + lm;
          const bf16x8 vf = *reinterpret_cast<const bf16x8*>(
              sh + LDS_V + h * 4096 + d * 128 + (((unsigned)(ks * 64 + lg * 16)) ^ ((unsigned)((d & 7) << 4))));
#pragma unroll
          for (int mt = 0; mt < 4; ++mt)
            oacc[mt][nt] = __builtin_amdgcn_mfma_f32_16x16x32_bf16(pa[mt], vf, oacc[mt][nt], 0, 0, 0);
        }
      }
#pragma unroll
      for (int mt = 0; mt < 4; ++mt)
#pragma unroll
        for (int reg = 0; reg < 4; ++reg) {
          const int l = mt * 16 + lg * 4 + reg;
#pragma unroll
          for (int nt = 0; nt < 2; ++nt) {
            const int d = nt * 16 + lm;
            *(unsigned short*)(sh + LDS_Q + h * 5120 + l * 80 + 2 * d) = f2bf(oacc[mt][nt][reg]);
          }
        }
    }
  }
  __syncthreads();

  // ---------- phase 5: proj GEMM + residual (from XN+stats) + post-LN + store ----
  {
    float pog4[4], pob4[4];
#pragma unroll
    for (int nt = 0; nt < 4; ++nt) { pog4[nt] = postg[nt * 16 + lm]; pob4[nt] = postb[nt * 16 + lm]; }
    f32x4 acc[4][4];
#pragma unroll
    for (int i = 0; i < 4; ++i)
#pragma unroll
      for (int j = 0; j < 4; ++j) acc[i][j] = f32x4{0.f, 0.f, 0.f, 0.f};
    for (int ks = 0; ks < 8; ++ks) {
      bf16x8 bfr[4];
#pragma unroll
      for (int nt = 0; nt < 4; ++nt) {
        const int l = nt * 16 + lm;
        bfr[nt] = *reinterpret_cast<const bf16x8*>(sh + LDS_Q + (unsigned)ks * 5120 + l * 80 + lg * 16);
      }
#pragma unroll
      for (int mt = 0; mt < 4; ++mt) {
        const int c = w * 64 + mt * 16 + lm;
        const bf16x8 a = *reinterpret_cast<const bf16x8*>(
            (const unsigned char*)wp + ((size_t)c * 512 + ks * 64 + lg * 16));
#pragma unroll
        for (int nt = 0; nt < 4; ++nt)
          acc[mt][nt] = __builtin_amdgcn_mfma_f32_16x16x32_bf16(a, bfr[nt], acc[mt][nt], 0, 0, 0);
      }
    }
#pragma unroll
    for (int mt = 0; mt < 4; ++mt) {
#pragma unroll
      for (int reg = 0; reg < 4; ++reg) {
        const int c = w * 64 + mt * 16 + lg * 4 + reg;
        const float bp = bproj[c];
        const float2 ms = *reinterpret_cast<const float2*>(sh + LDS_ST + c * 8);
        float y[4];
        float s1 = 0.f, s2 = 0.f;
#pragma unroll
        for (int nt = 0; nt < 4; ++nt) {
          const int l = nt * 16 + lm;
          const float xh = bf2f(*(const unsigned short*)(
              sh + LDS_XN + l * 512 + (((unsigned)(2 * c)) ^ ((unsigned)((l & 7) << 4)))));
          const float xp = xh * ms.y + ms.x;            // reconstruct pre-norm input
          const float v = xp + acc[mt][nt][reg] + bp;
          y[nt] = v;
          s1 += v; s2 += v * v;
        }
        s1 += __shfl_xor(s1, 1); s2 += __shfl_xor(s2, 1);
        s1 += __shfl_xor(s1, 2); s2 += __shfl_xor(s2, 2);
        s1 += __shfl_xor(s1, 4); s2 += __shfl_xor(s2, 4);
        s1 += __shfl_xor(s1, 8); s2 += __shfl_xor(s2, 8);
        const float mean = s1 * (1.f / 64.f);
        const float var  = s2 * (1.f / 64.f) - mean * mean;
        const float rstd = rsqrtf(fmaxf(var, 0.f) + 1e-5f);
        float* orow = out + (size_t)b * 16384 + (size_t)c * 64;
#pragma unroll
        for (int nt = 0; nt < 4; ++nt) {
          const int l = nt * 16 + lm;
          const float v = y[nt];
          orow[l] = v + (v - mean) * rstd * pog4[nt] + pob4[nt];
        }
      }
    }
  }
}

extern "C" void kernel_launch(void* const* d_in, const int* in_sizes, int n_in,
                              void* d_out, int out_size, void* d_ws, size_t ws_size,
                              hipStream_t stream) {
  const float* X     = (const float*)d_in[0];
  const float* preg  = (const float*)d_in[1];
  const float* preb  = (const float*)d_in[2];
  const float* postg = (const float*)d_in[3];
  const float* postb = (const float*)d_in[4];
  const float* Wqkv  = (const float*)d_in[5];
  const float* bqkv  = (const float*)d_in[6];
  const float* Wproj = (const float*)d_in[7];
  const float* bproj = (const float*)d_in[8];
  const float* table = (const float*)d_in[9];

  unsigned short* wq = (unsigned short*)d_ws;                    // 768*256 bf16
  unsigned short* wp = (unsigned short*)((char*)d_ws + 393216);  // 256*256 bf16
  float* biasg       = (float*)((char*)d_ws + 524288);           // 8*64*64 f32
  float* rowsum      = (float*)((char*)d_ws + 655360);           // 768 f32

  prep_kernel<<<768, 256, 0, stream>>>(Wqkv, Wproj, table, wq, wp, biasg, rowsum);
  win_attn_kernel<<<2048, 256, 0, stream>>>(X, preg, preb, postg, postb,
                                            bqkv, bproj, wq, wp, biasg, rowsum,
                                            (float*)d_out);
}

// Round 3
// 307.104 us; speedup vs baseline: 1.5602x; 1.5602x over previous
//
#include <hip/hip_runtime.h>

typedef __bf16 bf16x8 __attribute__((ext_vector_type(8)));
typedef float  f32x4  __attribute__((ext_vector_type(4)));
typedef unsigned short ushort4v __attribute__((ext_vector_type(4)));

#define DEVI static __device__ __forceinline__

DEVI unsigned short f2bf(float f) {
  union { float f; unsigned u; } v; v.f = f;
  unsigned u = v.u;
  u += 0x7fffu + ((u >> 16) & 1u);
  return (unsigned short)(u >> 16);
}
DEVI float bf2f(unsigned short s) {
  union { unsigned u; float f; } v; v.u = ((unsigned)s) << 16;
  return v.f;
}

// ---------------- prep: weights -> bf16, rel-pos bias expand, Wqkv rowsums ----
__global__ void prep_kernel(const float* __restrict__ Wqkv, const float* __restrict__ Wproj,
                            const float* __restrict__ table,
                            unsigned short* __restrict__ wq, unsigned short* __restrict__ wp,
                            float* __restrict__ biasg, float* __restrict__ rowsum) {
  const int i = blockIdx.x * 256 + threadIdx.x;
  if (i < 768 * 256) wq[i] = f2bf(Wqkv[i]);
  if (i < 256 * 256) wp[i] = f2bf(Wproj[i]);
  if (i < 8 * 64 * 64) {
    const int h = i >> 12, r = (i >> 6) & 63, c = i & 63;
    const int ridx = ((r >> 3) - (c >> 3) + 7) * 15 + ((r & 7) - (c & 7) + 7);
    biasg[i] = table[ridx * 8 + h];
  }
  if (i < 768) {
    const float4* p = reinterpret_cast<const float4*>(Wqkv + (size_t)i * 256);
    float s = 0.f;
#pragma unroll
    for (int j = 0; j < 64; ++j) { const float4 a = p[j]; s += a.x + a.y + a.z + a.w; }
    rowsum[i] = s;
  }
}

// LDS layout (bytes):
//  XN @ 0      : 64 rows x 512B  xhat bf16 [l][c], XOR-swizzled; alive ph1->ph5
//  ST @ 32768  : 256 x {mean, sigma} f32 (2048B); alive ph1->ph5
//  Q  @ 34816  : [8][64][80B] q bf16 [h][l][d]; ao overlays after ph4 barrier
//  K  @ 75776  : [8][64][80B]
//  V  @ 116736 : [8][32][128B] v bf16 [h][d][m'], XOR-swizzled rows
//  XW @ 34816  : raw window f32 [cc][r] rows 272B (overlays Q/K; dead after ph1)
//  P  @ 34816 + w*8192 : per-wave P buffers (overlay Q/K after frag preload)
//  YO @ 75776  : [256][256B] f32 output bounce (overlays K/V; ph5 only)
#define LDS_XN 0u
#define LDS_ST 32768u
#define LDS_Q  34816u
#define LDS_K  75776u
#define LDS_V  116736u
#define LDS_XW 34816u
#define LDS_YO 75776u
#define LDS_TOTAL 149504u

__global__ void __launch_bounds__(512, 2)
win_attn_kernel(const float* __restrict__ X,
                const float* __restrict__ preg, const float* __restrict__ preb,
                const float* __restrict__ postg, const float* __restrict__ postb,
                const float* __restrict__ bqkv, const float* __restrict__ bproj,
                const unsigned short* __restrict__ wq, const unsigned short* __restrict__ wp,
                const float* __restrict__ biasg, const float* __restrict__ rowsum,
                float* __restrict__ out) {
  __shared__ alignas(16) unsigned char sh[LDS_TOTAL];
  const int tid = threadIdx.x;
  const int w = tid >> 6;
  const int lane = tid & 63, lm = lane & 15, lg = lane >> 4;
  const int orig = blockIdx.x;
  const int b = (orig & 7) * 256 + (orig >> 3);
  const int n = b >> 8, gh = (b >> 4) & 15, gw = b & 15;
  const size_t wbase = (size_t)n * 4194304 + (size_t)gh * 1024 + (size_t)gw * 8;

  // ---------- phase 0: coalesced stage of raw window -> XW[cc][r] f32 ----------
  {
#pragma unroll
    for (int i = 0; i < 4; ++i) {
      const int rid = i * 512 + tid;
      const int cc = rid >> 3, w0 = rid & 7;
      const float* xb = X + wbase + (size_t)cc * 16384 + w0 * 128;
      const float4 a  = *reinterpret_cast<const float4*>(xb);
      const float4 bv = *reinterpret_cast<const float4*>(xb + 4);
      const unsigned xorv = (cc & 64) ? 16u : 0u;
      unsigned char* dst = sh + LDS_XW + (unsigned)cc * 272u + (unsigned)w0 * 32u;
      *reinterpret_cast<float4*>(dst + xorv)         = a;
      *reinterpret_cast<float4*>(dst + (16u ^ xorv)) = bv;
    }
  }
  __syncthreads();

  // ---------- phase 1: pre-LN per attn-channel c (2 threads/channel) ----------
  // xp[c][l] = X[n][(c&3)*64+l][gh*8 + (c>>5)][gw*8 + ((c>>2)&7)]
  {
    const int c = tid >> 1, half = tid & 1;
    const int r = ((c >> 5) << 3) + ((c >> 2) & 7);
    const unsigned base = LDS_XW + (unsigned)(c & 3) * (64u * 272u)
                        + 4u * (unsigned)(r ^ ((c & 1) << 2));
    float fv[32];
    float s1 = 0.f, s2 = 0.f;
#pragma unroll
    for (int i = 0; i < 32; ++i) {
      const int l = half * 32 + i;
      const float v = *reinterpret_cast<const float*>(sh + base + (unsigned)l * 272u);
      fv[i] = v; s1 += v; s2 += v * v;
    }
    s1 += __shfl_xor(s1, 1);
    s2 += __shfl_xor(s2, 1);
    const float mean = s1 * (1.f / 64.f);
    float var = s2 * (1.f / 64.f) - mean * mean;
    var = fmaxf(var, 0.f) + 1e-5f;
    const float rstd = rsqrtf(var);
    const float sig  = var * rstd;      // sqrt(var+eps)
#pragma unroll
    for (int i = 0; i < 32; ++i) {
      const int l = half * 32 + i;
      *(unsigned short*)(sh + LDS_XN + l * 512 +
          (((unsigned)(2 * c)) ^ ((unsigned)((l & 7) << 4)))) = f2bf((fv[i] - mean) * rstd);
    }
    if (!half) *reinterpret_cast<float2*>(sh + LDS_ST + c * 8) = float2{mean, sig};
  }
  __syncthreads();

  // ---------- phase 2: QKV GEMM (wave w -> rows w*96..w*96+95), route q/k/v ----
  {
    float pg4[4], pb4[4];
#pragma unroll
    for (int nt = 0; nt < 4; ++nt) { pg4[nt] = preg[nt * 16 + lm]; pb4[nt] = preb[nt * 16 + lm]; }
    const int wbase96 = w * 96;
    f32x4 acc[6][4];
#pragma unroll
    for (int i = 0; i < 6; ++i)
#pragma unroll
      for (int j = 0; j < 4; ++j) acc[i][j] = f32x4{0.f, 0.f, 0.f, 0.f};
    for (int ks = 0; ks < 8; ++ks) {
      bf16x8 bfrag[4];
#pragma unroll
      for (int nt = 0; nt < 4; ++nt) {
        const int l = nt * 16 + lm;
        bfrag[nt] = *reinterpret_cast<const bf16x8*>(
            sh + LDS_XN + l * 512 + (((unsigned)(ks * 64 + lg * 16)) ^ ((unsigned)((l & 7) << 4))));
      }
#pragma unroll
      for (int m4 = 0; m4 < 6; ++m4) {
        const int o = wbase96 + m4 * 16 + lm;
        const bf16x8 a = *reinterpret_cast<const bf16x8*>(
            (const unsigned char*)wq + ((size_t)o * 512 + ks * 64 + lg * 16));
#pragma unroll
        for (int nt = 0; nt < 4; ++nt)
          acc[m4][nt] = __builtin_amdgcn_mfma_f32_16x16x32_bf16(a, bfrag[nt], acc[m4][nt], 0, 0, 0);
      }
    }
    f32x4 rs4[6], bq4[6];
#pragma unroll
    for (int m4 = 0; m4 < 6; ++m4) {
      rs4[m4] = *reinterpret_cast<const f32x4*>(rowsum + wbase96 + m4 * 16 + lg * 4);
      bq4[m4] = *reinterpret_cast<const f32x4*>(bqkv   + wbase96 + m4 * 16 + lg * 4);
    }
#pragma unroll
    for (int m4 = 0; m4 < 6; ++m4) {
      const int ob = wbase96 + m4 * 16;
      if (ob < 512) {                         // q or k: packed b64 writes
        const unsigned qkbase = (ob < 256) ? LDS_Q : LDS_K;
        const int o0 = (ob & 255) + lg * 4;
        const int h = o0 >> 5, d0 = o0 & 31;
#pragma unroll
        for (int nt = 0; nt < 4; ++nt) {
          const int l = nt * 16 + lm;
          ushort4v pk;
#pragma unroll
          for (int reg = 0; reg < 4; ++reg)
            pk[reg] = f2bf(pg4[nt] * acc[m4][nt][reg] + pb4[nt] * rs4[m4][reg] + bq4[m4][reg]);
          *reinterpret_cast<ushort4v*>(sh + qkbase + h * 5120 + l * 80 + 2 * d0) = pk;
        }
      } else {                                // v: scalar routed writes
        const int o20 = ob - 512 + lg * 4;
#pragma unroll
        for (int reg = 0; reg < 4; ++reg) {
          const int o2 = o20 + reg;
          const int h = o2 >> 5, d = o2 & 31;
          const float rs = rs4[m4][reg], bq = bq4[m4][reg];
#pragma unroll
          for (int nt = 0; nt < 4; ++nt) {
            const int l = nt * 16 + lm;
            *(unsigned short*)(sh + LDS_V + h * 4096 + d * 128 +
                (((unsigned)(2 * l)) ^ ((unsigned)((d & 7) << 4)))) =
                f2bf(pg4[nt] * acc[m4][nt][reg] + pb4[nt] * rs + bq);
          }
        }
      }
    }
  }
  __syncthreads();

  // ---------- phase 3: L2-normalize q and k rows (1 Q row + 1 K row / thread) --
  {
#pragma unroll
    for (int j = 0; j < 2; ++j) {
      const unsigned base = j ? LDS_K : LDS_Q;
      const int h = tid >> 6, l = tid & 63;
      unsigned* row = (unsigned*)(sh + base + h * 5120 + l * 80);
      unsigned u[16];
      float ss = 0.f;
#pragma unroll
      for (int t2 = 0; t2 < 16; ++t2) {
        u[t2] = row[t2];
        const float lo = bf2f((unsigned short)(u[t2] & 0xffffu));
        const float hi = bf2f((unsigned short)(u[t2] >> 16));
        ss += lo * lo + hi * hi;
      }
      const float inv = 1.f / fmaxf(sqrtf(ss), 1e-12f);
#pragma unroll
      for (int t2 = 0; t2 < 16; ++t2) {
        const float lo = bf2f((unsigned short)(u[t2] & 0xffffu)) * inv;
        const float hi = bf2f((unsigned short)(u[t2] >> 16)) * inv;
        row[t2] = (unsigned)f2bf(lo) | (((unsigned)f2bf(hi)) << 16);
      }
    }
  }
  __syncthreads();

  // ---------- phase 4: attention, wave w -> head w; P overlays Q/K after preload
  {
    const int h = w;
    const unsigned pbase = LDS_Q + (unsigned)w * 8192u;
    bf16x8 qf[4], kf[4];
#pragma unroll
    for (int mt = 0; mt < 4; ++mt)
      qf[mt] = *reinterpret_cast<const bf16x8*>(sh + LDS_Q + h * 5120 + (mt * 16 + lm) * 80 + lg * 16);
#pragma unroll
    for (int nt = 0; nt < 4; ++nt)
      kf[nt] = *reinterpret_cast<const bf16x8*>(sh + LDS_K + h * 5120 + (nt * 16 + lm) * 80 + lg * 16);
    __syncthreads();   // all frag preloads done before P overwrites Q/K

    // bias preload (overlaps following MFMAs)
    const float* bh = biasg + h * 4096;
    float p[4][4][4];
#pragma unroll
    for (int mt = 0; mt < 4; ++mt)
#pragma unroll
      for (int reg = 0; reg < 4; ++reg) {
        const int rrow = mt * 16 + lg * 4 + reg;
#pragma unroll
        for (int nt = 0; nt < 4; ++nt)
          p[mt][nt][reg] = bh[rrow * 64 + nt * 16 + lm];
      }

    f32x4 s[4][4];
#pragma unroll
    for (int nt = 0; nt < 4; ++nt)
#pragma unroll
      for (int mt = 0; mt < 4; ++mt)
        s[mt][nt] = __builtin_amdgcn_mfma_f32_16x16x32_bf16(qf[mt], kf[nt], f32x4{0.f,0.f,0.f,0.f}, 0, 0, 0);

    float rinv[4][4];
#pragma unroll
    for (int mt = 0; mt < 4; ++mt)
#pragma unroll
      for (int reg = 0; reg < 4; ++reg) {
        float m = -1e30f;
#pragma unroll
        for (int nt = 0; nt < 4; ++nt) {
          const float v = s[mt][nt][reg] + p[mt][nt][reg];
          p[mt][nt][reg] = v;
          m = fmaxf(m, v);
        }
        m = fmaxf(m, __shfl_xor(m, 1));
        m = fmaxf(m, __shfl_xor(m, 2));
        m = fmaxf(m, __shfl_xor(m, 4));
        m = fmaxf(m, __shfl_xor(m, 8));
        float sum = 0.f;
#pragma unroll
        for (int nt = 0; nt < 4; ++nt) {
          const float e = __expf(p[mt][nt][reg] - m);
          p[mt][nt][reg] = e;
          sum += e;
        }
        sum += __shfl_xor(sum, 1);
        sum += __shfl_xor(sum, 2);
        sum += __shfl_xor(sum, 4);
        sum += __shfl_xor(sum, 8);
        rinv[mt][reg] = 1.f / sum;
      }
#pragma unroll
    for (int mt = 0; mt < 4; ++mt)
#pragma unroll
      for (int reg = 0; reg < 4; ++reg) {
        const int rrow = mt * 16 + lg * 4 + reg;
#pragma unroll
        for (int nt = 0; nt < 4; ++nt) {
          const int ccol = nt * 16 + lm;
          *(unsigned short*)(sh + pbase + rrow * 128 +
              (((unsigned)(2 * ccol)) ^ ((unsigned)((rrow & 7) << 4)))) = f2bf(p[mt][nt][reg] * rinv[mt][reg]);
        }
      }
    f32x4 oacc[4][2];
#pragma unroll
    for (int mt = 0; mt < 4; ++mt) { oacc[mt][0] = f32x4{0.f,0.f,0.f,0.f}; oacc[mt][1] = f32x4{0.f,0.f,0.f,0.f}; }
#pragma unroll
    for (int ks = 0; ks < 2; ++ks) {
      bf16x8 pa[4];
#pragma unroll
      for (int mt = 0; mt < 4; ++mt) {
        const int l = mt * 16 + lm;
        pa[mt] = *reinterpret_cast<const bf16x8*>(
            sh + pbase + l * 128 + (((unsigned)(ks * 64 + lg * 16)) ^ ((unsigned)((l & 7) << 4))));
      }
#pragma unroll
      for (int nt = 0; nt < 2; ++nt) {
        const int d = nt * 16 + lm;
        const bf16x8 vf = *reinterpret_cast<const bf16x8*>(
            sh + LDS_V + h * 4096 + d * 128 + (((unsigned)(ks * 64 + lg * 16)) ^ ((unsigned)((d & 7) << 4))));
#pragma unroll
        for (int mt = 0; mt < 4; ++mt)
          oacc[mt][nt] = __builtin_amdgcn_mfma_f32_16x16x32_bf16(pa[mt], vf, oacc[mt][nt], 0, 0, 0);
      }
    }
    __syncthreads();   // all P reads done before ao overwrites Q region
#pragma unroll
    for (int mt = 0; mt < 4; ++mt)
#pragma unroll
      for (int reg = 0; reg < 4; ++reg) {
        const int l = mt * 16 + lg * 4 + reg;
#pragma unroll
        for (int nt = 0; nt < 2; ++nt) {
          const int d = nt * 16 + lm;
          *(unsigned short*)(sh + LDS_Q + h * 5120 + l * 80 + 2 * d) = f2bf(oacc[mt][nt][reg]);
        }
      }
  }
  __syncthreads();

  // ---------- phase 5: proj GEMM (wave w -> rows w*32..w*32+31) + post-LN ------
  {
    float pog4[4], pob4[4];
#pragma unroll
    for (int nt = 0; nt < 4; ++nt) { pog4[nt] = postg[nt * 16 + lm]; pob4[nt] = postb[nt * 16 + lm]; }
    f32x4 acc[2][4];
#pragma unroll
    for (int i = 0; i < 2; ++i)
#pragma unroll
      for (int j = 0; j < 4; ++j) acc[i][j] = f32x4{0.f, 0.f, 0.f, 0.f};
    for (int ks = 0; ks < 8; ++ks) {
      bf16x8 bfr[4];
#pragma unroll
      for (int nt = 0; nt < 4; ++nt) {
        const int l = nt * 16 + lm;
        bfr[nt] = *reinterpret_cast<const bf16x8*>(sh + LDS_Q + (unsigned)ks * 5120 + l * 80 + lg * 16);
      }
#pragma unroll
      for (int mt = 0; mt < 2; ++mt) {
        const int c = w * 32 + mt * 16 + lm;
        const bf16x8 a = *reinterpret_cast<const bf16x8*>(
            (const unsigned char*)wp + ((size_t)c * 512 + ks * 64 + lg * 16));
#pragma unroll
        for (int nt = 0; nt < 4; ++nt)
          acc[mt][nt] = __builtin_amdgcn_mfma_f32_16x16x32_bf16(a, bfr[nt], acc[mt][nt], 0, 0, 0);
      }
    }
#pragma unroll
    for (int mt = 0; mt < 2; ++mt) {
      const float4 bp4 = *reinterpret_cast<const float4*>(bproj + w * 32 + mt * 16 + lg * 4);
#pragma unroll
      for (int reg = 0; reg < 4; ++reg) {
        const int c = w * 32 + mt * 16 + lg * 4 + reg;
        const float bp = ((const float*)&bp4)[reg];
        const float2 ms = *reinterpret_cast<const float2*>(sh + LDS_ST + c * 8);
        float y[4];
        float s1 = 0.f, s2 = 0.f;
#pragma unroll
        for (int nt = 0; nt < 4; ++nt) {
          const int l = nt * 16 + lm;
          const float xh = bf2f(*(const unsigned short*)(
              sh + LDS_XN + l * 512 + (((unsigned)(2 * c)) ^ ((unsigned)((l & 7) << 4)))));
          const float v = xh * ms.y + ms.x + acc[mt][nt][reg] + bp;
          y[nt] = v;
          s1 += v; s2 += v * v;
        }
        s1 += __shfl_xor(s1, 1); s2 += __shfl_xor(s2, 1);
        s1 += __shfl_xor(s1, 2); s2 += __shfl_xor(s2, 2);
        s1 += __shfl_xor(s1, 4); s2 += __shfl_xor(s2, 4);
        s1 += __shfl_xor(s1, 8); s2 += __shfl_xor(s2, 8);
        const float mean = s1 * (1.f / 64.f);
        const float var  = s2 * (1.f / 64.f) - mean * mean;
        const float rstd = rsqrtf(fmaxf(var, 0.f) + 1e-5f);
#pragma unroll
        for (int nt = 0; nt < 4; ++nt) {
          const int l = nt * 16 + lm;
          const float v = y[nt];
          *reinterpret_cast<float*>(sh + LDS_YO + (unsigned)c * 256u +
              (((unsigned)(4 * l)) ^ ((unsigned)((c & 1) << 6)))) =
              v + (v - mean) * rstd * pog4[nt] + pob4[nt];
        }
      }
    }
  }
  __syncthreads();

  // ---------- phase 6: coalesced store from YO ----------
  {
    const size_t ob = (size_t)b * 16384;
#pragma unroll
    for (int i = 0; i < 8; ++i) {
      const int flat = i * 512 + tid;           // 16B chunk id
      const int c = flat >> 4, ch = flat & 15;
      const float4 v = *reinterpret_cast<const float4*>(
          sh + LDS_YO + (unsigned)c * 256u + (((unsigned)(ch * 16)) ^ ((unsigned)((c & 1) << 6))));
      *reinterpret_cast<float4*>(out + ob + (size_t)flat * 4) = v;
    }
  }
}

extern "C" void kernel_launch(void* const* d_in, const int* in_sizes, int n_in,
                              void* d_out, int out_size, void* d_ws, size_t ws_size,
                              hipStream_t stream) {
  const float* X     = (const float*)d_in[0];
  const float* preg  = (const float*)d_in[1];
  const float* preb  = (const float*)d_in[2];
  const float* postg = (const float*)d_in[3];
  const float* postb = (const float*)d_in[4];
  const float* Wqkv  = (const float*)d_in[5];
  const float* bqkv  = (const float*)d_in[6];
  const float* Wproj = (const float*)d_in[7];
  const float* bproj = (const float*)d_in[8];
  const float* table = (const float*)d_in[9];

  unsigned short* wq = (unsigned short*)d_ws;                    // 768*256 bf16
  unsigned short* wp = (unsigned short*)((char*)d_ws + 393216);  // 256*256 bf16
  float* biasg       = (float*)((char*)d_ws + 524288);           // 8*64*64 f32
  float* rowsum      = (float*)((char*)d_ws + 655360);           // 768 f32

  prep_kernel<<<768, 256, 0, stream>>>(Wqkv, Wproj, table, wq, wp, biasg, rowsum);
  win_attn_kernel<<<2048, 512, 0, stream>>>(X, preg, preb, postg, postb,
                                            bqkv, bproj, wq, wp, biasg, rowsum,
                                            (float*)d_out);
}

// Round 4
// 293.181 us; speedup vs baseline: 1.6343x; 1.0475x over previous
//
#include <hip/hip_runtime.h>

typedef __bf16 bf16x8 __attribute__((ext_vector_type(8)));
typedef float  f32x4  __attribute__((ext_vector_type(4)));
typedef unsigned short ushort4v __attribute__((ext_vector_type(4)));

#define DEVI static __device__ __forceinline__

DEVI unsigned short f2bf(float f) {          // native cvt (v_cvt_pk_bf16_f32)
  __bf16 h = (__bf16)f;
  return __builtin_bit_cast(unsigned short, h);
}
DEVI float bf2f(unsigned short s) {
  union { unsigned u; float f; } v; v.u = ((unsigned)s) << 16;
  return v.f;
}

// ---------------- prep: weights -> bf16, rel-pos bias expand, Wqkv rowsums ----
__global__ void prep_kernel(const float* __restrict__ Wqkv, const float* __restrict__ Wproj,
                            const float* __restrict__ table,
                            unsigned short* __restrict__ wq, unsigned short* __restrict__ wp,
                            float* __restrict__ biasg, float* __restrict__ rowsum) {
  const int i = blockIdx.x * 256 + threadIdx.x;
  if (i < 768 * 256) wq[i] = f2bf(Wqkv[i]);
  if (i < 256 * 256) wp[i] = f2bf(Wproj[i]);
  if (i < 8 * 64 * 64) {
    const int h = i >> 12, r = (i >> 6) & 63, c = i & 63;
    const int ridx = ((r >> 3) - (c >> 3) + 7) * 15 + ((r & 7) - (c & 7) + 7);
    biasg[i] = table[ridx * 8 + h];
  }
  if (i < 768) {
    const float4* p = reinterpret_cast<const float4*>(Wqkv + (size_t)i * 256);
    float s = 0.f;
#pragma unroll
    for (int j = 0; j < 64; ++j) { const float4 a = p[j]; s += a.x + a.y + a.z + a.w; }
    rowsum[i] = s;
  }
}

// LDS layout (bytes):
//  XN @ 0      : 64 rows x 512B  xhat bf16 [l][c], XOR-swizzled; alive ph1->ph5
//  ST @ 32768  : 256 x {mean, sigma} f32 (2048B); alive ph1->ph5
//  Q  @ 34816  : [8][64][80B] q bf16 [h][l][d]; per-wave P rows 0-39 + ao overlay (own head only)
//  K  @ 75776  : [8][64][80B]; per-wave P rows 40-63 overlay (own head only)
//  V  @ 116736 : [8][32][128B] v bf16 [h][d][m'], XOR-swizzled rows
//  XW @ 34816  : raw window f32 [cc][r] rows 272B (overlays Q/K; dead after ph1)
//  YO @ 75776  : [256][256B] f32 output bounce (overlays K/V; ph5-6 only)
#define LDS_XN 0u
#define LDS_ST 32768u
#define LDS_Q  34816u
#define LDS_K  75776u
#define LDS_V  116736u
#define LDS_XW 34816u
#define LDS_YO 75776u
#define LDS_TOTAL 149504u

__global__ void __launch_bounds__(512, 2)
win_attn_kernel(const float* __restrict__ X,
                const float* __restrict__ preg, const float* __restrict__ preb,
                const float* __restrict__ postg, const float* __restrict__ postb,
                const float* __restrict__ bqkv, const float* __restrict__ bproj,
                const unsigned short* __restrict__ wq, const unsigned short* __restrict__ wp,
                const float* __restrict__ biasg, const float* __restrict__ rowsum,
                float* __restrict__ out) {
  __shared__ alignas(16) unsigned char sh[LDS_TOTAL];
  const int tid = threadIdx.x;
  const int w = tid >> 6;
  const int lane = tid & 63, lm = lane & 15, lg = lane >> 4;
  const int orig = blockIdx.x;
  const int b = (orig & 7) * 256 + (orig >> 3);
  const int n = b >> 8, gh = (b >> 4) & 15, gw = b & 15;
  const size_t wbase = (size_t)n * 4194304 + (size_t)gh * 1024 + (size_t)gw * 8;

  // ---------- phase 0: coalesced stage of raw window -> XW[cc][r] f32 ----------
  {
#pragma unroll
    for (int i = 0; i < 4; ++i) {
      const int rid = i * 512 + tid;
      const int cc = rid >> 3, w0 = rid & 7;
      const float* xb = X + wbase + (size_t)cc * 16384 + w0 * 128;
      const float4 a  = *reinterpret_cast<const float4*>(xb);
      const float4 bv = *reinterpret_cast<const float4*>(xb + 4);
      const unsigned xorv = (cc & 64) ? 16u : 0u;
      unsigned char* dst = sh + LDS_XW + (unsigned)cc * 272u + (unsigned)w0 * 32u;
      *reinterpret_cast<float4*>(dst + xorv)         = a;
      *reinterpret_cast<float4*>(dst + (16u ^ xorv)) = bv;
    }
  }
  __syncthreads();

  // ---------- phase 1: pre-LN per attn-channel c (2 threads/channel) ----------
  // xp[c][l] = X[n][(c&3)*64+l][gh*8 + (c>>5)][gw*8 + ((c>>2)&7)]
  {
    const int c = tid >> 1, half = tid & 1;
    const int r = ((c >> 5) << 3) + ((c >> 2) & 7);
    const unsigned base = LDS_XW + (unsigned)(c & 3) * (64u * 272u)
                        + 4u * (unsigned)(r ^ ((c & 1) << 2));
    float fv[32];
    float s1 = 0.f, s2 = 0.f;
#pragma unroll
    for (int i = 0; i < 32; ++i) {
      const int l = half * 32 + i;
      const float v = *reinterpret_cast<const float*>(sh + base + (unsigned)l * 272u);
      fv[i] = v; s1 += v; s2 += v * v;
    }
    s1 += __shfl_xor(s1, 1);
    s2 += __shfl_xor(s2, 1);
    const float mean = s1 * (1.f / 64.f);
    float var = s2 * (1.f / 64.f) - mean * mean;
    var = fmaxf(var, 0.f) + 1e-5f;
    const float rstd = rsqrtf(var);
    const float sig  = var * rstd;      // sqrt(var+eps)
#pragma unroll
    for (int i = 0; i < 32; ++i) {
      const int l = half * 32 + i;
      *(unsigned short*)(sh + LDS_XN + l * 512 +
          (((unsigned)(2 * c)) ^ ((unsigned)((l & 7) << 4)))) = f2bf((fv[i] - mean) * rstd);
    }
    if (!half) *reinterpret_cast<float2*>(sh + LDS_ST + c * 8) = float2{mean, sig};
  }
  __syncthreads();

  // ---------- phase 2: QKV GEMM (wave w -> rows w*96..+95) + folded q/k L2-norm
  {
    float pg4[4], pb4[4];
#pragma unroll
    for (int nt = 0; nt < 4; ++nt) { pg4[nt] = preg[nt * 16 + lm]; pb4[nt] = preb[nt * 16 + lm]; }
    const int wbase96 = w * 96;
    const unsigned char* abase = (const unsigned char*)wq + ((size_t)(wbase96 + lm) * 512 + lg * 16);
    f32x4 acc[6][4];
#pragma unroll
    for (int i = 0; i < 6; ++i)
#pragma unroll
      for (int j = 0; j < 4; ++j) acc[i][j] = f32x4{0.f, 0.f, 0.f, 0.f};
    bf16x8 acur[6];
#pragma unroll
    for (int m4 = 0; m4 < 6; ++m4)
      acur[m4] = *reinterpret_cast<const bf16x8*>(abase + m4 * 8192);
#pragma unroll
    for (int ks = 0; ks < 8; ++ks) {
      bf16x8 anxt[6];
      if (ks < 7) {
#pragma unroll
        for (int m4 = 0; m4 < 6; ++m4)
          anxt[m4] = *reinterpret_cast<const bf16x8*>(abase + m4 * 8192 + (ks + 1) * 64);
      }
      bf16x8 bfrag[4];
#pragma unroll
      for (int nt = 0; nt < 4; ++nt) {
        const int l = nt * 16 + lm;
        bfrag[nt] = *reinterpret_cast<const bf16x8*>(
            sh + LDS_XN + l * 512 + (((unsigned)(ks * 64 + lg * 16)) ^ ((unsigned)((l & 7) << 4))));
      }
#pragma unroll
      for (int m4 = 0; m4 < 6; ++m4)
#pragma unroll
        for (int nt = 0; nt < 4; ++nt)
          acc[m4][nt] = __builtin_amdgcn_mfma_f32_16x16x32_bf16(acur[m4], bfrag[nt], acc[m4][nt], 0, 0, 0);
      if (ks < 7) {
#pragma unroll
        for (int m4 = 0; m4 < 6; ++m4) acur[m4] = anxt[m4];
      }
    }
    // epilogue: affine + bias in place
#pragma unroll
    for (int m4 = 0; m4 < 6; ++m4) {
      const f32x4 rs4 = *reinterpret_cast<const f32x4*>(rowsum + wbase96 + m4 * 16 + lg * 4);
      const f32x4 bq4 = *reinterpret_cast<const f32x4*>(bqkv   + wbase96 + m4 * 16 + lg * 4);
#pragma unroll
      for (int nt = 0; nt < 4; ++nt)
#pragma unroll
        for (int reg = 0; reg < 4; ++reg)
          acc[m4][nt][reg] = pg4[nt] * acc[m4][nt][reg] + pb4[nt] * rs4[reg] + bq4[reg];
    }
    // folded L2-norm for q/k heads (wave-uniform branch per half-head pair)
#pragma unroll
    for (int hh = 0; hh < 3; ++hh) {
      const int hh3 = w * 3 + hh;          // head-block index 0..23 (q:0-7 k:8-15 v:16-23)
      if (hh3 < 16) {
#pragma unroll
        for (int nt = 0; nt < 4; ++nt) {
          float ss = 0.f;
#pragma unroll
          for (int half = 0; half < 2; ++half)
#pragma unroll
            for (int reg = 0; reg < 4; ++reg) {
              const float v = acc[2 * hh + half][nt][reg];
              ss += v * v;
            }
          ss += __shfl_xor(ss, 16);
          ss += __shfl_xor(ss, 32);
          const float inv = 1.f / fmaxf(sqrtf(ss), 1e-12f);
#pragma unroll
          for (int half = 0; half < 2; ++half)
#pragma unroll
            for (int reg = 0; reg < 4; ++reg)
              acc[2 * hh + half][nt][reg] *= inv;
        }
      }
    }
    // route writes
#pragma unroll
    for (int hh = 0; hh < 3; ++hh) {
      const int hh3 = w * 3 + hh;
      if (hh3 < 16) {
        const unsigned base = (hh3 < 8) ? (LDS_Q + (unsigned)hh3 * 5120u)
                                        : (LDS_K + (unsigned)(hh3 - 8) * 5120u);
#pragma unroll
        for (int half = 0; half < 2; ++half) {
          const int d0 = half * 16 + lg * 4;
#pragma unroll
          for (int nt = 0; nt < 4; ++nt) {
            const int l = nt * 16 + lm;
            ushort4v pk;
#pragma unroll
            for (int reg = 0; reg < 4; ++reg) pk[reg] = f2bf(acc[2 * hh + half][nt][reg]);
            *reinterpret_cast<ushort4v*>(sh + base + l * 80 + 2 * d0) = pk;
          }
        }
      } else {
        const int hv = hh3 - 16;
#pragma unroll
        for (int half = 0; half < 2; ++half)
#pragma unroll
          for (int reg = 0; reg < 4; ++reg) {
            const int d = half * 16 + lg * 4 + reg;
#pragma unroll
            for (int nt = 0; nt < 4; ++nt) {
              const int l = nt * 16 + lm;
              *(unsigned short*)(sh + LDS_V + hv * 4096 + d * 128 +
                  (((unsigned)(2 * l)) ^ ((unsigned)((d & 7) << 4)))) =
                  f2bf(acc[2 * hh + half][nt][reg]);
            }
          }
      }
    }
  }
  __syncthreads();

  // ---------- phase 4: attention, wave w -> head w; fully barrier-free ----------
  // P (64 rows x 128B, flat 8KB) overlays OWN head's q rows (0-39) + k rows (40-63);
  // ao overlays OWN head's q rows. All hazards are same-wave dataflow.
  {
    const int h = w;
    const unsigned qh = LDS_Q + (unsigned)w * 5120u;
    const unsigned kh = LDS_K + (unsigned)w * 5120u;
    bf16x8 qf[4], kf[4], vf[2][2];
#pragma unroll
    for (int mt = 0; mt < 4; ++mt)
      qf[mt] = *reinterpret_cast<const bf16x8*>(sh + qh + (mt * 16 + lm) * 80 + lg * 16);
#pragma unroll
    for (int nt = 0; nt < 4; ++nt)
      kf[nt] = *reinterpret_cast<const bf16x8*>(sh + kh + (nt * 16 + lm) * 80 + lg * 16);
#pragma unroll
    for (int ks = 0; ks < 2; ++ks)
#pragma unroll
      for (int nt = 0; nt < 2; ++nt) {
        const int d = nt * 16 + lm;
        vf[ks][nt] = *reinterpret_cast<const bf16x8*>(
            sh + LDS_V + h * 4096 + d * 128 + (((unsigned)(ks * 64 + lg * 16)) ^ ((unsigned)((d & 7) << 4))));
      }
    // bias preload (L2 scalar loads overlap the MFMAs below)
    const float* bh = biasg + h * 4096;
    float p[4][4][4];
#pragma unroll
    for (int mt = 0; mt < 4; ++mt)
#pragma unroll
      for (int reg = 0; reg < 4; ++reg) {
        const int rrow = mt * 16 + lg * 4 + reg;
#pragma unroll
        for (int nt = 0; nt < 4; ++nt)
          p[mt][nt][reg] = bh[rrow * 64 + nt * 16 + lm];
      }
    f32x4 s[4][4];
#pragma unroll
    for (int nt = 0; nt < 4; ++nt)
#pragma unroll
      for (int mt = 0; mt < 4; ++mt)
        s[mt][nt] = __builtin_amdgcn_mfma_f32_16x16x32_bf16(qf[mt], kf[nt], f32x4{0.f,0.f,0.f,0.f}, 0, 0, 0);
    float rinv[4][4];
#pragma unroll
    for (int mt = 0; mt < 4; ++mt)
#pragma unroll
      for (int reg = 0; reg < 4; ++reg) {
        float m = -1e30f;
#pragma unroll
        for (int nt = 0; nt < 4; ++nt) {
          const float v = s[mt][nt][reg] + p[mt][nt][reg];
          p[mt][nt][reg] = v;
          m = fmaxf(m, v);
        }
        m = fmaxf(m, __shfl_xor(m, 1));
        m = fmaxf(m, __shfl_xor(m, 2));
        m = fmaxf(m, __shfl_xor(m, 4));
        m = fmaxf(m, __shfl_xor(m, 8));
        float sum = 0.f;
#pragma unroll
        for (int nt = 0; nt < 4; ++nt) {
          const float e = __expf(p[mt][nt][reg] - m);
          p[mt][nt][reg] = e;
          sum += e;
        }
        sum += __shfl_xor(sum, 1);
        sum += __shfl_xor(sum, 2);
        sum += __shfl_xor(sum, 4);
        sum += __shfl_xor(sum, 8);
        rinv[mt][reg] = 1.f / sum;
      }
    // P writes into own q(0-39)/k(40-63) rows
#pragma unroll
    for (int mt = 0; mt < 4; ++mt)
#pragma unroll
      for (int reg = 0; reg < 4; ++reg) {
        const int rrow = mt * 16 + lg * 4 + reg;
#pragma unroll
        for (int nt = 0; nt < 4; ++nt) {
          const int ccol = nt * 16 + lm;
          const unsigned flat = (unsigned)(rrow * 128) +
              (((unsigned)(2 * ccol)) ^ ((unsigned)((rrow & 7) << 4)));
          const unsigned addr = (flat < 5120u) ? (qh + flat) : (kh + flat - 5120u);
          *(unsigned short*)(sh + addr) = f2bf(p[mt][nt][reg] * rinv[mt][reg]);
        }
      }
    // PV
    f32x4 oacc[4][2];
#pragma unroll
    for (int mt = 0; mt < 4; ++mt) { oacc[mt][0] = f32x4{0.f,0.f,0.f,0.f}; oacc[mt][1] = f32x4{0.f,0.f,0.f,0.f}; }
#pragma unroll
    for (int ks = 0; ks < 2; ++ks) {
      bf16x8 pa[4];
#pragma unroll
      for (int mt = 0; mt < 4; ++mt) {
        const int l = mt * 16 + lm;
        const unsigned flat = (unsigned)(l * 128) +
            (((unsigned)(ks * 64 + lg * 16)) ^ ((unsigned)((l & 7) << 4)));
        const unsigned addr = (flat < 5120u) ? (qh + flat) : (kh + flat - 5120u);
        pa[mt] = *reinterpret_cast<const bf16x8*>(sh + addr);
      }
#pragma unroll
      for (int nt = 0; nt < 2; ++nt)
#pragma unroll
        for (int mt = 0; mt < 4; ++mt)
          oacc[mt][nt] = __builtin_amdgcn_mfma_f32_16x16x32_bf16(pa[mt], vf[ks][nt], oacc[mt][nt], 0, 0, 0);
    }
    // ao -> own q rows [l][d] (all P reads retired by dataflow)
#pragma unroll
    for (int mt = 0; mt < 4; ++mt)
#pragma unroll
      for (int reg = 0; reg < 4; ++reg) {
        const int l = mt * 16 + lg * 4 + reg;
#pragma unroll
        for (int nt = 0; nt < 2; ++nt) {
          const int d = nt * 16 + lm;
          *(unsigned short*)(sh + qh + l * 80 + 2 * d) = f2bf(oacc[mt][nt][reg]);
        }
      }
  }
  __syncthreads();

  // ---------- phase 5: proj GEMM (wave w -> rows w*32..+31) + residual + post-LN
  {
    float pog4[4], pob4[4];
#pragma unroll
    for (int nt = 0; nt < 4; ++nt) { pog4[nt] = postg[nt * 16 + lm]; pob4[nt] = postb[nt * 16 + lm]; }
    const unsigned char* abase = (const unsigned char*)wp + ((size_t)(w * 32 + lm) * 512 + lg * 16);
    f32x4 acc[2][4];
#pragma unroll
    for (int i = 0; i < 2; ++i)
#pragma unroll
      for (int j = 0; j < 4; ++j) acc[i][j] = f32x4{0.f, 0.f, 0.f, 0.f};
    bf16x8 acur[2];
#pragma unroll
    for (int mt = 0; mt < 2; ++mt)
      acur[mt] = *reinterpret_cast<const bf16x8*>(abase + mt * 8192);
#pragma unroll
    for (int ks = 0; ks < 8; ++ks) {
      bf16x8 anxt[2];
      if (ks < 7) {
#pragma unroll
        for (int mt = 0; mt < 2; ++mt)
          anxt[mt] = *reinterpret_cast<const bf16x8*>(abase + mt * 8192 + (ks + 1) * 64);
      }
      bf16x8 bfr[4];
#pragma unroll
      for (int nt = 0; nt < 4; ++nt) {
        const int l = nt * 16 + lm;
        bfr[nt] = *reinterpret_cast<const bf16x8*>(sh + LDS_Q + (unsigned)ks * 5120 + l * 80 + lg * 16);
      }
#pragma unroll
      for (int mt = 0; mt < 2; ++mt)
#pragma unroll
        for (int nt = 0; nt < 4; ++nt)
          acc[mt][nt] = __builtin_amdgcn_mfma_f32_16x16x32_bf16(acur[mt], bfr[nt], acc[mt][nt], 0, 0, 0);
      if (ks < 7) {
#pragma unroll
        for (int mt = 0; mt < 2; ++mt) acur[mt] = anxt[mt];
      }
    }
#pragma unroll
    for (int mt = 0; mt < 2; ++mt) {
      const float4 bp4 = *reinterpret_cast<const float4*>(bproj + w * 32 + mt * 16 + lg * 4);
#pragma unroll
      for (int reg = 0; reg < 4; ++reg) {
        const int c = w * 32 + mt * 16 + lg * 4 + reg;
        const float bp = ((const float*)&bp4)[reg];
        const float2 ms = *reinterpret_cast<const float2*>(sh + LDS_ST + c * 8);
        float y[4];
        float s1 = 0.f, s2 = 0.f;
#pragma unroll
        for (int nt = 0; nt < 4; ++nt) {
          const int l = nt * 16 + lm;
          const float xh = bf2f(*(const unsigned short*)(
              sh + LDS_XN + l * 512 + (((unsigned)(2 * c)) ^ ((unsigned)((l & 7) << 4)))));
          const float v = xh * ms.y + ms.x + acc[mt][nt][reg] + bp;
          y[nt] = v;
          s1 += v; s2 += v * v;
        }
        s1 += __shfl_xor(s1, 1); s2 += __shfl_xor(s2, 1);
        s1 += __shfl_xor(s1, 2); s2 += __shfl_xor(s2, 2);
        s1 += __shfl_xor(s1, 4); s2 += __shfl_xor(s2, 4);
        s1 += __shfl_xor(s1, 8); s2 += __shfl_xor(s2, 8);
        const float mean = s1 * (1.f / 64.f);
        const float var  = s2 * (1.f / 64.f) - mean * mean;
        const float rstd = rsqrtf(fmaxf(var, 0.f) + 1e-5f);
#pragma unroll
        for (int nt = 0; nt < 4; ++nt) {
          const int l = nt * 16 + lm;
          const float v = y[nt];
          *reinterpret_cast<float*>(sh + LDS_YO + (unsigned)c * 256u +
              (((unsigned)(4 * l)) ^ ((unsigned)((c & 1) << 6)))) =
              v + (v - mean) * rstd * pog4[nt] + pob4[nt];
        }
      }
    }
  }
  __syncthreads();

  // ---------- phase 6: coalesced store from YO ----------
  {
    const size_t ob = (size_t)b * 16384;
#pragma unroll
    for (int i = 0; i < 8; ++i) {
      const int flat = i * 512 + tid;           // 16B chunk id
      const int c = flat >> 4, ch = flat & 15;
      const float4 v = *reinterpret_cast<const float4*>(
          sh + LDS_YO + (unsigned)c * 256u + (((unsigned)(ch * 16)) ^ ((unsigned)((c & 1) << 6))));
      *reinterpret_cast<float4*>(out + ob + (size_t)flat * 4) = v;
    }
  }
}

extern "C" void kernel_launch(void* const* d_in, const int* in_sizes, int n_in,
                              void* d_out, int out_size, void* d_ws, size_t ws_size,
                              hipStream_t stream) {
  const float* X     = (const float*)d_in[0];
  const float* preg  = (const float*)d_in[1];
  const float* preb  = (const float*)d_in[2];
  const float* postg = (const float*)d_in[3];
  const float* postb = (const float*)d_in[4];
  const float* Wqkv  = (const float*)d_in[5];
  const float* bqkv  = (const float*)d_in[6];
  const float* Wproj = (const float*)d_in[7];
  const float* bproj = (const float*)d_in[8];
  const float* table = (const float*)d_in[9];

  unsigned short* wq = (unsigned short*)d_ws;                    // 768*256 bf16
  unsigned short* wp = (unsigned short*)((char*)d_ws + 393216);  // 256*256 bf16
  float* biasg       = (float*)((char*)d_ws + 524288);           // 8*64*64 f32
  float* rowsum      = (float*)((char*)d_ws + 655360);           // 768 f32

  prep_kernel<<<768, 256, 0, stream>>>(Wqkv, Wproj, table, wq, wp, biasg, rowsum);
  win_attn_kernel<<<2048, 512, 0, stream>>>(X, preg, preb, postg, postb,
                                            bqkv, bproj, wq, wp, biasg, rowsum,
                                            (float*)d_out);
}

// Round 10
// 292.329 us; speedup vs baseline: 1.6390x; 1.0029x over previous
//
#include <hip/hip_runtime.h>

typedef __bf16 bf16x8 __attribute__((ext_vector_type(8)));
typedef float  f32x4  __attribute__((ext_vector_type(4)));
typedef unsigned short ushort4v __attribute__((ext_vector_type(4)));

#define DEVI static __device__ __forceinline__

// Drain all outstanding LDS ops, then pin program order (rule #18).
#define LDS_FENCE() do { \
  asm volatile("s_waitcnt lgkmcnt(0)" ::: "memory"); \
  __builtin_amdgcn_sched_barrier(0); \
} while (0)

DEVI unsigned short f2bf(float f) {          // native cvt
  __bf16 h = (__bf16)f;
  return __builtin_bit_cast(unsigned short, h);
}
DEVI float bf2f(unsigned short s) {
  union { unsigned u; float f; } v; v.u = ((unsigned)s) << 16;
  return v.f;
}

// ---------------- prep: weights -> bf16, rel-pos bias expand, Wqkv rowsums ----
__global__ void prep_kernel(const float* __restrict__ Wqkv, const float* __restrict__ Wproj,
                            const float* __restrict__ table,
                            unsigned short* __restrict__ wq, unsigned short* __restrict__ wp,
                            float* __restrict__ biasg, float* __restrict__ rowsum) {
  const int i = blockIdx.x * 256 + threadIdx.x;
  if (i < 768 * 256) wq[i] = f2bf(Wqkv[i]);
  if (i < 256 * 256) wp[i] = f2bf(Wproj[i]);
  if (i < 8 * 64 * 64) {
    const int h = i >> 12, r = (i >> 6) & 63, c = i & 63;
    const int ridx = ((r >> 3) - (c >> 3) + 7) * 15 + ((r & 7) - (c & 7) + 7);
    biasg[i] = table[ridx * 8 + h];
  }
  if (i < 768) {
    const float4* p = reinterpret_cast<const float4*>(Wqkv + (size_t)i * 256);
    float s = 0.f;
#pragma unroll
    for (int j = 0; j < 64; ++j) { const float4 a = p[j]; s += a.x + a.y + a.z + a.w; }
    rowsum[i] = s;
  }
}

// LDS layout (bytes) — identical to the replay-proven R4 kernel:
//  XN @ 0      : 64 rows x 512B  xhat bf16 [l][c], XOR-swizzled; alive ph1->ph5
//  ST @ 32768  : 256 x {mean, sigma} f32 (2048B); alive ph1->ph5
//  Q  @ 34816  : [8][64][80B] q bf16 [h][l][d]; per-wave P rows 0-39 + ao overlay (own head only)
//  K  @ 75776  : [8][64][80B]; per-wave P rows 40-63 overlay (own head only)
//  V  @ 116736 : [8][32][128B] v bf16 [h][d][m'], XOR-swizzled rows
//  XW @ 34816  : raw window f32 [cc][r] rows 272B (overlays Q/K; dead after ph1)
//  YO @ 75776  : [256][256B] f32 output bounce (overlays K/V; ph5-6 only)
#define LDS_XN 0u
#define LDS_ST 32768u
#define LDS_Q  34816u
#define LDS_K  75776u
#define LDS_V  116736u
#define LDS_XW 34816u
#define LDS_YO 75776u
#define LDS_TOTAL 149504u

__global__ void __launch_bounds__(512, 2)
win_attn_kernel(const float* __restrict__ X,
                const float* __restrict__ preg, const float* __restrict__ preb,
                const float* __restrict__ postg, const float* __restrict__ postb,
                const float* __restrict__ bqkv, const float* __restrict__ bproj,
                const unsigned short* __restrict__ wq, const unsigned short* __restrict__ wp,
                const float* __restrict__ biasg, const float* __restrict__ rowsum,
                float* __restrict__ out) {
  __shared__ alignas(16) unsigned char sh[LDS_TOTAL];
  const int tid = threadIdx.x;
  const int w = tid >> 6;
  const int lane = tid & 63, lm = lane & 15, lg = lane >> 4;
  const int orig = blockIdx.x;
  const int b = (orig & 7) * 256 + (orig >> 3);
  const int n = b >> 8, gh = (b >> 4) & 15, gw = b & 15;
  const size_t wbase = (size_t)n * 4194304 + (size_t)gh * 1024 + (size_t)gw * 8;

  // ---------- phase 0 (R4 verbatim): coalesced stage raw window -> XW[cc][r] f32
  {
#pragma unroll
    for (int i = 0; i < 4; ++i) {
      const int rid = i * 512 + tid;
      const int cc = rid >> 3, w0 = rid & 7;
      const float* xb = X + wbase + (size_t)cc * 16384 + w0 * 128;
      const float4 a  = *reinterpret_cast<const float4*>(xb);
      const float4 bv = *reinterpret_cast<const float4*>(xb + 4);
      const unsigned xorv = (cc & 64) ? 16u : 0u;
      unsigned char* dst = sh + LDS_XW + (unsigned)cc * 272u + (unsigned)w0 * 32u;
      *reinterpret_cast<float4*>(dst + xorv)         = a;
      *reinterpret_cast<float4*>(dst + (16u ^ xorv)) = bv;
    }
  }
  __syncthreads();

  // ---------- phase 1 (R4 verbatim): pre-LN per attn-channel (2 threads/channel)
  // xp[c][l] = X[n][(c&3)*64+l][gh*8 + (c>>5)][gw*8 + ((c>>2)&7)]
  {
    const int c = tid >> 1, half = tid & 1;
    const int r = ((c >> 5) << 3) + ((c >> 2) & 7);
    const unsigned base = LDS_XW + (unsigned)(c & 3) * (64u * 272u)
                        + 4u * (unsigned)(r ^ ((c & 1) << 2));
    float fv[32];
    float s1 = 0.f, s2 = 0.f;
#pragma unroll
    for (int i = 0; i < 32; ++i) {
      const int l = half * 32 + i;
      const float v = *reinterpret_cast<const float*>(sh + base + (unsigned)l * 272u);
      fv[i] = v; s1 += v; s2 += v * v;
    }
    s1 += __shfl_xor(s1, 1);
    s2 += __shfl_xor(s2, 1);
    const float mean = s1 * (1.f / 64.f);
    float var = s2 * (1.f / 64.f) - mean * mean;
    var = fmaxf(var, 0.f) + 1e-5f;
    const float rstd = rsqrtf(var);
    const float sig  = var * rstd;      // sqrt(var+eps)
#pragma unroll
    for (int i = 0; i < 32; ++i) {
      const int l = half * 32 + i;
      *(unsigned short*)(sh + LDS_XN + l * 512 +
          (((unsigned)(2 * c)) ^ ((unsigned)((l & 7) << 4)))) = f2bf((fv[i] - mean) * rstd);
    }
    if (!half) *reinterpret_cast<float2*>(sh + LDS_ST + c * 8) = float2{mean, sig};
  }
  __syncthreads();

  // ---------- phase 2 (R4 verbatim): QKV GEMM + folded q/k L2-norm -------------
  {
    float pg4[4], pb4[4];
#pragma unroll
    for (int nt = 0; nt < 4; ++nt) { pg4[nt] = preg[nt * 16 + lm]; pb4[nt] = preb[nt * 16 + lm]; }
    const int wbase96 = w * 96;
    const unsigned char* abase = (const unsigned char*)wq + ((size_t)(wbase96 + lm) * 512 + lg * 16);
    f32x4 acc[6][4];
#pragma unroll
    for (int i = 0; i < 6; ++i)
#pragma unroll
      for (int j = 0; j < 4; ++j) acc[i][j] = f32x4{0.f, 0.f, 0.f, 0.f};
    bf16x8 acur[6];
#pragma unroll
    for (int m4 = 0; m4 < 6; ++m4)
      acur[m4] = *reinterpret_cast<const bf16x8*>(abase + m4 * 8192);
#pragma unroll
    for (int ks = 0; ks < 8; ++ks) {
      bf16x8 anxt[6];
      if (ks < 7) {
#pragma unroll
        for (int m4 = 0; m4 < 6; ++m4)
          anxt[m4] = *reinterpret_cast<const bf16x8*>(abase + m4 * 8192 + (ks + 1) * 64);
      }
      bf16x8 bfrag[4];
#pragma unroll
      for (int nt = 0; nt < 4; ++nt) {
        const int l = nt * 16 + lm;
        bfrag[nt] = *reinterpret_cast<const bf16x8*>(
            sh + LDS_XN + l * 512 + (((unsigned)(ks * 64 + lg * 16)) ^ ((unsigned)((l & 7) << 4))));
      }
#pragma unroll
      for (int m4 = 0; m4 < 6; ++m4)
#pragma unroll
        for (int nt = 0; nt < 4; ++nt)
          acc[m4][nt] = __builtin_amdgcn_mfma_f32_16x16x32_bf16(acur[m4], bfrag[nt], acc[m4][nt], 0, 0, 0);
      if (ks < 7) {
#pragma unroll
        for (int m4 = 0; m4 < 6; ++m4) acur[m4] = anxt[m4];
      }
    }
    // epilogue: affine + bias in place
#pragma unroll
    for (int m4 = 0; m4 < 6; ++m4) {
      const f32x4 rs4 = *reinterpret_cast<const f32x4*>(rowsum + wbase96 + m4 * 16 + lg * 4);
      const f32x4 bq4 = *reinterpret_cast<const f32x4*>(bqkv   + wbase96 + m4 * 16 + lg * 4);
#pragma unroll
      for (int nt = 0; nt < 4; ++nt)
#pragma unroll
        for (int reg = 0; reg < 4; ++reg)
          acc[m4][nt][reg] = pg4[nt] * acc[m4][nt][reg] + pb4[nt] * rs4[reg] + bq4[reg];
    }
    // folded L2-norm for q/k heads
#pragma unroll
    for (int hh = 0; hh < 3; ++hh) {
      const int hh3 = w * 3 + hh;
      if (hh3 < 16) {
#pragma unroll
        for (int nt = 0; nt < 4; ++nt) {
          float ss = 0.f;
#pragma unroll
          for (int half = 0; half < 2; ++half)
#pragma unroll
            for (int reg = 0; reg < 4; ++reg) {
              const float v = acc[2 * hh + half][nt][reg];
              ss += v * v;
            }
          ss += __shfl_xor(ss, 16);
          ss += __shfl_xor(ss, 32);
          const float inv = 1.f / fmaxf(sqrtf(ss), 1e-12f);
#pragma unroll
          for (int half = 0; half < 2; ++half)
#pragma unroll
            for (int reg = 0; reg < 4; ++reg)
              acc[2 * hh + half][nt][reg] *= inv;
        }
      }
    }
    // route writes
#pragma unroll
    for (int hh = 0; hh < 3; ++hh) {
      const int hh3 = w * 3 + hh;
      if (hh3 < 16) {
        const unsigned base = (hh3 < 8) ? (LDS_Q + (unsigned)hh3 * 5120u)
                                        : (LDS_K + (unsigned)(hh3 - 8) * 5120u);
#pragma unroll
        for (int half = 0; half < 2; ++half) {
          const int d0 = half * 16 + lg * 4;
#pragma unroll
          for (int nt = 0; nt < 4; ++nt) {
            const int l = nt * 16 + lm;
            ushort4v pk;
#pragma unroll
            for (int reg = 0; reg < 4; ++reg) pk[reg] = f2bf(acc[2 * hh + half][nt][reg]);
            *reinterpret_cast<ushort4v*>(sh + base + l * 80 + 2 * d0) = pk;
          }
        }
      } else {
        const int hv = hh3 - 16;
#pragma unroll
        for (int half = 0; half < 2; ++half)
#pragma unroll
          for (int reg = 0; reg < 4; ++reg) {
            const int d = half * 16 + lg * 4 + reg;
#pragma unroll
            for (int nt = 0; nt < 4; ++nt) {
              const int l = nt * 16 + lm;
              *(unsigned short*)(sh + LDS_V + hv * 4096 + d * 128 +
                  (((unsigned)(2 * l)) ^ ((unsigned)((d & 7) << 4)))) =
                  f2bf(acc[2 * hh + half][nt][reg]);
            }
          }
      }
    }
  }
  __syncthreads();

  // ---------- phase 4: attention, wave w -> head w (R4 + hardening fences) -----
  {
    const int h = w;
    const unsigned qh = LDS_Q + (unsigned)w * 5120u;
    const unsigned kh = LDS_K + (unsigned)w * 5120u;
    bf16x8 qf[4], kf[4], vf[2][2];
#pragma unroll
    for (int mt = 0; mt < 4; ++mt)
      qf[mt] = *reinterpret_cast<const bf16x8*>(sh + qh + (mt * 16 + lm) * 80 + lg * 16);
#pragma unroll
    for (int nt = 0; nt < 4; ++nt)
      kf[nt] = *reinterpret_cast<const bf16x8*>(sh + kh + (nt * 16 + lm) * 80 + lg * 16);
#pragma unroll
    for (int ks = 0; ks < 2; ++ks)
#pragma unroll
      for (int nt = 0; nt < 2; ++nt) {
        const int d = nt * 16 + lm;
        vf[ks][nt] = *reinterpret_cast<const bf16x8*>(
            sh + LDS_V + h * 4096 + d * 128 + (((unsigned)(ks * 64 + lg * 16)) ^ ((unsigned)((d & 7) << 4))));
      }
    LDS_FENCE();       // fragments provably in registers...
    __syncthreads();   // ...block-wide, before any P byte is written

    // bias preload (L2 scalar loads overlap the MFMAs below)
    const float* bh = biasg + h * 4096;
    float p[4][4][4];
#pragma unroll
    for (int mt = 0; mt < 4; ++mt)
#pragma unroll
      for (int reg = 0; reg < 4; ++reg) {
        const int rrow = mt * 16 + lg * 4 + reg;
#pragma unroll
        for (int nt = 0; nt < 4; ++nt)
          p[mt][nt][reg] = bh[rrow * 64 + nt * 16 + lm];
      }
    f32x4 s[4][4];
#pragma unroll
    for (int nt = 0; nt < 4; ++nt)
#pragma unroll
      for (int mt = 0; mt < 4; ++mt)
        s[mt][nt] = __builtin_amdgcn_mfma_f32_16x16x32_bf16(qf[mt], kf[nt], f32x4{0.f,0.f,0.f,0.f}, 0, 0, 0);
    float rinv[4][4];
#pragma unroll
    for (int mt = 0; mt < 4; ++mt)
#pragma unroll
      for (int reg = 0; reg < 4; ++reg) {
        float m = -1e30f;
#pragma unroll
        for (int nt = 0; nt < 4; ++nt) {
          const float v = s[mt][nt][reg] + p[mt][nt][reg];
          p[mt][nt][reg] = v;
          m = fmaxf(m, v);
        }
        m = fmaxf(m, __shfl_xor(m, 1));
        m = fmaxf(m, __shfl_xor(m, 2));
        m = fmaxf(m, __shfl_xor(m, 4));
        m = fmaxf(m, __shfl_xor(m, 8));
        float sum = 0.f;
#pragma unroll
        for (int nt = 0; nt < 4; ++nt) {
          const float e = __expf(p[mt][nt][reg] - m);
          p[mt][nt][reg] = e;
          sum += e;
        }
        sum += __shfl_xor(sum, 1);
        sum += __shfl_xor(sum, 2);
        sum += __shfl_xor(sum, 4);
        sum += __shfl_xor(sum, 8);
        rinv[mt][reg] = 1.f / sum;
      }
    // P writes into own q(0-39)/k(40-63) rows
#pragma unroll
    for (int mt = 0; mt < 4; ++mt)
#pragma unroll
      for (int reg = 0; reg < 4; ++reg) {
        const int rrow = mt * 16 + lg * 4 + reg;
#pragma unroll
        for (int nt = 0; nt < 4; ++nt) {
          const int ccol = nt * 16 + lm;
          const unsigned flat = (unsigned)(rrow * 128) +
              (((unsigned)(2 * ccol)) ^ ((unsigned)((rrow & 7) << 4)));
          const unsigned addr = (flat < 5120u) ? (qh + flat) : (kh + flat - 5120u);
          *(unsigned short*)(sh + addr) = f2bf(p[mt][nt][reg] * rinv[mt][reg]);
        }
      }
    LDS_FENCE();       // P committed before pa reads
    // PV
    f32x4 oacc[4][2];
#pragma unroll
    for (int mt = 0; mt < 4; ++mt) { oacc[mt][0] = f32x4{0.f,0.f,0.f,0.f}; oacc[mt][1] = f32x4{0.f,0.f,0.f,0.f}; }
#pragma unroll
    for (int ks = 0; ks < 2; ++ks) {
      bf16x8 pa[4];
#pragma unroll
      for (int mt = 0; mt < 4; ++mt) {
        const int l = mt * 16 + lm;
        const unsigned flat = (unsigned)(l * 128) +
            (((unsigned)(ks * 64 + lg * 16)) ^ ((unsigned)((l & 7) << 4)));
        const unsigned addr = (flat < 5120u) ? (qh + flat) : (kh + flat - 5120u);
        pa[mt] = *reinterpret_cast<const bf16x8*>(sh + addr);
      }
#pragma unroll
      for (int nt2 = 0; nt2 < 2; ++nt2)
#pragma unroll
        for (int mt = 0; mt < 4; ++mt)
          oacc[mt][nt2] = __builtin_amdgcn_mfma_f32_16x16x32_bf16(pa[mt], vf[ks][nt2], oacc[mt][nt2], 0, 0, 0);
    }
    LDS_FENCE();       // pa reads retired before ao overwrites the same bytes
#pragma unroll
    for (int mt = 0; mt < 4; ++mt)
#pragma unroll
      for (int reg = 0; reg < 4; ++reg) {
        const int l = mt * 16 + 4 * lg + reg;
#pragma unroll
        for (int nt2 = 0; nt2 < 2; ++nt2) {
          const int d = nt2 * 16 + lm;
          *(unsigned short*)(sh + qh + l * 80 + 2 * d) = f2bf(oacc[mt][nt2][reg]);
        }
      }
  }
  __syncthreads();

  // ---------- phase 5 (R4 verbatim): proj GEMM + residual (XN+ST) + post-LN ----
  {
    float pog4[4], pob4[4];
#pragma unroll
    for (int nt = 0; nt < 4; ++nt) { pog4[nt] = postg[nt * 16 + lm]; pob4[nt] = postb[nt * 16 + lm]; }
    const unsigned char* abase = (const unsigned char*)wp + ((size_t)(w * 32 + lm) * 512 + lg * 16);
    f32x4 acc[2][4];
#pragma unroll
    for (int i = 0; i < 2; ++i)
#pragma unroll
      for (int j = 0; j < 4; ++j) acc[i][j] = f32x4{0.f, 0.f, 0.f, 0.f};
    bf16x8 acur[2];
#pragma unroll
    for (int mt = 0; mt < 2; ++mt)
      acur[mt] = *reinterpret_cast<const bf16x8*>(abase + mt * 8192);
#pragma unroll
    for (int ks = 0; ks < 8; ++ks) {
      bf16x8 anxt[2];
      if (ks < 7) {
#pragma unroll
        for (int mt = 0; mt < 2; ++mt)
          anxt[mt] = *reinterpret_cast<const bf16x8*>(abase + mt * 8192 + (ks + 1) * 64);
      }
      bf16x8 bfr[4];
#pragma unroll
      for (int nt = 0; nt < 4; ++nt) {
        const int l = nt * 16 + lm;
        bfr[nt] = *reinterpret_cast<const bf16x8*>(sh + LDS_Q + (unsigned)ks * 5120 + l * 80 + lg * 16);
      }
#pragma unroll
      for (int mt = 0; mt < 2; ++mt)
#pragma unroll
        for (int nt = 0; nt < 4; ++nt)
          acc[mt][nt] = __builtin_amdgcn_mfma_f32_16x16x32_bf16(acur[mt], bfr[nt], acc[mt][nt], 0, 0, 0);
      if (ks < 7) {
#pragma unroll
        for (int mt = 0; mt < 2; ++mt) acur[mt] = anxt[mt];
      }
    }
#pragma unroll
    for (int mt = 0; mt < 2; ++mt) {
      const float4 bp4 = *reinterpret_cast<const float4*>(bproj + w * 32 + mt * 16 + lg * 4);
#pragma unroll
      for (int reg = 0; reg < 4; ++reg) {
        const int c = w * 32 + mt * 16 + lg * 4 + reg;
        const float bp = ((const float*)&bp4)[reg];
        const float2 ms = *reinterpret_cast<const float2*>(sh + LDS_ST + c * 8);
        float y[4];
        float s1 = 0.f, s2 = 0.f;
#pragma unroll
        for (int nt = 0; nt < 4; ++nt) {
          const int l = nt * 16 + lm;
          const float xh = bf2f(*(const unsigned short*)(
              sh + LDS_XN + l * 512 + (((unsigned)(2 * c)) ^ ((unsigned)((l & 7) << 4)))));
          const float v = xh * ms.y + ms.x + acc[mt][nt][reg] + bp;
          y[nt] = v;
          s1 += v; s2 += v * v;
        }
        s1 += __shfl_xor(s1, 1); s2 += __shfl_xor(s2, 1);
        s1 += __shfl_xor(s1, 2); s2 += __shfl_xor(s2, 2);
        s1 += __shfl_xor(s1, 4); s2 += __shfl_xor(s2, 4);
        s1 += __shfl_xor(s1, 8); s2 += __shfl_xor(s2, 8);
        const float mean = s1 * (1.f / 64.f);
        const float var  = s2 * (1.f / 64.f) - mean * mean;
        const float rstd = rsqrtf(fmaxf(var, 0.f) + 1e-5f);
#pragma unroll
        for (int nt = 0; nt < 4; ++nt) {
          const int l = nt * 16 + lm;
          const float v = y[nt];
          *reinterpret_cast<float*>(sh + LDS_YO + (unsigned)c * 256u +
              (((unsigned)(4 * l)) ^ ((unsigned)((c & 1) << 6)))) =
              v + (v - mean) * rstd * pog4[nt] + pob4[nt];
        }
      }
    }
  }
  __syncthreads();

  // ---------- phase 6 (R4 verbatim): coalesced store from YO ----------
  {
    const size_t ob = (size_t)b * 16384;
#pragma unroll
    for (int i = 0; i < 8; ++i) {
      const int flat = i * 512 + tid;           // 16B chunk id
      const int c = flat >> 4, ch = flat & 15;
      const float4 v = *reinterpret_cast<const float4*>(
          sh + LDS_YO + (unsigned)c * 256u + (((unsigned)(ch * 16)) ^ ((unsigned)((c & 1) << 6))));
      *reinterpret_cast<float4*>(out + ob + (size_t)flat * 4) = v;
    }
  }
}

extern "C" void kernel_launch(void* const* d_in, const int* in_sizes, int n_in,
                              void* d_out, int out_size, void* d_ws, size_t ws_size,
                              hipStream_t stream) {
  const float* X     = (const float*)d_in[0];
  const float* preg  = (const float*)d_in[1];
  const float* preb  = (const float*)d_in[2];
  const float* postg = (const float*)d_in[3];
  const float* postb = (const float*)d_in[4];
  const float* Wqkv  = (const float*)d_in[5];
  const float* bqkv  = (const float*)d_in[6];
  const float* Wproj = (const float*)d_in[7];
  const float* bproj = (const float*)d_in[8];
  const float* table = (const float*)d_in[9];

  unsigned short* wq = (unsigned short*)d_ws;                    // 768*256 bf16
  unsigned short* wp = (unsigned short*)((char*)d_ws + 393216);  // 256*256 bf16
  float* biasg       = (float*)((char*)d_ws + 524288);           // 8*64*64 f32
  float* rowsum      = (float*)((char*)d_ws + 655360);           // 768 f32

  prep_kernel<<<768, 256, 0, stream>>>(Wqkv, Wproj, table, wq, wp, biasg, rowsum);
  win_attn_kernel<<<2048, 512, 0, stream>>>(X, preg, preb, postg, postb,
                                            bqkv, bproj, wq, wp, biasg, rowsum,
                                            (float*)d_out);
}

// Round 12
// 259.159 us; speedup vs baseline: 1.8488x; 1.1280x over previous
//
#include <hip/hip_runtime.h>

typedef __bf16 bf16x8 __attribute__((ext_vector_type(8)));
typedef float  f32x4  __attribute__((ext_vector_type(4)));

#define DEVI static __device__ __forceinline__

// Drain all outstanding LDS ops, then pin program order (rule #18).
#define LDS_FENCE() do { \
  asm volatile("s_waitcnt lgkmcnt(0)" ::: "memory"); \
  __builtin_amdgcn_sched_barrier(0); \
} while (0)

DEVI unsigned short f2bf(float f) {          // native cvt
  __bf16 h = (__bf16)f;
  return __builtin_bit_cast(unsigned short, h);
}
DEVI float bf2f(unsigned short s) {
  union { unsigned u; float f; } v; v.u = ((unsigned)s) << 16;
  return v.f;
}

// ---------------- prep: weights -> bf16, rel-pos bias expand, Wqkv rowsums ----
__global__ void prep_kernel(const float* __restrict__ Wqkv, const float* __restrict__ Wproj,
                            const float* __restrict__ table,
                            unsigned short* __restrict__ wq, unsigned short* __restrict__ wp,
                            float* __restrict__ biasg, float* __restrict__ rowsum) {
  const int i = blockIdx.x * 256 + threadIdx.x;
  if (i < 768 * 256) wq[i] = f2bf(Wqkv[i]);
  if (i < 256 * 256) wp[i] = f2bf(Wproj[i]);
  if (i < 8 * 64 * 64) {
    const int h = i >> 12, r = (i >> 6) & 63, c = i & 63;
    const int ridx = ((r >> 3) - (c >> 3) + 7) * 15 + ((r & 7) - (c & 7) + 7);
    biasg[i] = table[ridx * 8 + h];
  }
  if (i < 768) {
    const float4* p = reinterpret_cast<const float4*>(Wqkv + (size_t)i * 256);
    float s = 0.f;
#pragma unroll
    for (int j = 0; j < 64; ++j) { const float4 a = p[j]; s += a.x + a.y + a.z + a.w; }
    rowsum[i] = s;
  }
}

// LDS (104448 B, 1 block/CU — bisect round, no occupancy claim):
//  XN  @ 0     : 64 rows x 512B, xhat bf16 [l][c] XOR-swizzled; alive ph1->ph5
//  ST  @ 32768 : 256 x {mean, sigma} f32 (2048B); alive ph1->ph5
//  XW  @ 34816 : raw window f32 [cc][272B] (R10-verbatim staging; dead after ph1)
//  SCR @ 34816 : overlays dead XW. 8 waves x 4608B: vT [32][144B] (permuted cols),
//                then AO [64][64B] overlay. Phase 5: all waves read AO slots.
#define LDS_XN  0u
#define LDS_ST  32768u
#define LDS_XW  34816u
#define LDS_SCR 34816u
#define LDS_TOTAL 104448u

__global__ void __launch_bounds__(512, 2)
win_attn_kernel(const float* __restrict__ X,
                const float* __restrict__ preg, const float* __restrict__ preb,
                const float* __restrict__ postg, const float* __restrict__ postb,
                const float* __restrict__ bqkv, const float* __restrict__ bproj,
                const unsigned short* __restrict__ wq, const unsigned short* __restrict__ wp,
                const float* __restrict__ biasg, const float* __restrict__ rowsum,
                float* __restrict__ out) {
  __shared__ alignas(16) unsigned char sh[LDS_TOTAL];
  const int tid = threadIdx.x;
  const int w = tid >> 6;
  const int lane = tid & 63, lm = lane & 15, lg = lane >> 4;
  const int orig = blockIdx.x;
  const int b = (orig & 7) * 256 + (orig >> 3);
  const int n = b >> 8, gh = (b >> 4) & 15, gw = b & 15;
  const size_t wbase = (size_t)n * 4194304 + (size_t)gh * 1024 + (size_t)gw * 8;

  // ---------- phase 0 (R10 verbatim): coalesced stage raw window -> XW[cc][r] f32
  {
#pragma unroll
    for (int i = 0; i < 4; ++i) {
      const int rid = i * 512 + tid;
      const int cc = rid >> 3, w0 = rid & 7;
      const float* xb = X + wbase + (size_t)cc * 16384 + w0 * 128;
      const float4 a  = *reinterpret_cast<const float4*>(xb);
      const float4 bv = *reinterpret_cast<const float4*>(xb + 4);
      const unsigned xorv = (cc & 64) ? 16u : 0u;
      unsigned char* dst = sh + LDS_XW + (unsigned)cc * 272u + (unsigned)w0 * 32u;
      *reinterpret_cast<float4*>(dst + xorv)         = a;
      *reinterpret_cast<float4*>(dst + (16u ^ xorv)) = bv;
    }
  }
  __syncthreads();

  // ---------- phase 1 (R10 verbatim): pre-LN per attn-channel (2 threads/channel)
  // xp[c][l] = X[n][(c&3)*64+l][gh*8 + (c>>5)][gw*8 + ((c>>2)&7)]
  {
    const int c = tid >> 1, half = tid & 1;
    const int r = ((c >> 5) << 3) + ((c >> 2) & 7);
    const unsigned base = LDS_XW + (unsigned)(c & 3) * (64u * 272u)
                        + 4u * (unsigned)(r ^ ((c & 1) << 2));
    float fv[32];
    float s1 = 0.f, s2 = 0.f;
#pragma unroll
    for (int i = 0; i < 32; ++i) {
      const int l = half * 32 + i;
      const float v = *reinterpret_cast<const float*>(sh + base + (unsigned)l * 272u);
      fv[i] = v; s1 += v; s2 += v * v;
    }
    s1 += __shfl_xor(s1, 1);
    s2 += __shfl_xor(s2, 1);
    const float mean = s1 * (1.f / 64.f);
    float var = s2 * (1.f / 64.f) - mean * mean;
    var = fmaxf(var, 0.f) + 1e-5f;
    const float rstd = rsqrtf(var);
    const float sig  = var * rstd;      // sqrt(var+eps)
#pragma unroll
    for (int i = 0; i < 32; ++i) {
      const int l = half * 32 + i;
      *(unsigned short*)(sh + LDS_XN + l * 512 +
          (((unsigned)(2 * c)) ^ ((unsigned)((l & 7) << 4)))) = f2bf((fv[i] - mean) * rstd);
    }
    if (!half) *reinterpret_cast<float2*>(sh + LDS_ST + c * 8) = float2{mean, sig};
  }
  // prefetch QKV A-fragments for head w (hidden under the barrier)
  const unsigned char* wqb = (const unsigned char*)wq;
  size_t aoff[6];
  bf16x8 acur[6];
#pragma unroll
  for (int t = 0; t < 6; ++t) {
    const int o = (t >> 1) * 256 + 32 * w + 16 * (t & 1) + lm;   // q/k/v of head w
    aoff[t] = (size_t)o * 512 + lg * 16;
    acur[t] = *reinterpret_cast<const bf16x8*>(wqb + aoff[t]);
  }
  __syncthreads();

  // ---------- phase 2: QKV GEMM, wave w -> head w's q,k,v (all in regs) -------
  float pg4[4], pb4[4];
#pragma unroll
  for (int nt = 0; nt < 4; ++nt) { pg4[nt] = preg[nt * 16 + lm]; pb4[nt] = preb[nt * 16 + lm]; }
  f32x4 acc6[6][4];
#pragma unroll
  for (int t = 0; t < 6; ++t)
#pragma unroll
    for (int j = 0; j < 4; ++j) acc6[t][j] = f32x4{0.f, 0.f, 0.f, 0.f};
#pragma unroll
  for (int ks = 0; ks < 8; ++ks) {
    bf16x8 anxt[6];
    if (ks < 7) {
#pragma unroll
      for (int t = 0; t < 6; ++t)
        anxt[t] = *reinterpret_cast<const bf16x8*>(wqb + aoff[t] + (ks + 1) * 64);
    }
    bf16x8 bfrag[4];
#pragma unroll
    for (int nt = 0; nt < 4; ++nt) {
      const int l = nt * 16 + lm;
      bfrag[nt] = *reinterpret_cast<const bf16x8*>(
          sh + LDS_XN + l * 512 + (((unsigned)(ks * 64 + lg * 16)) ^ ((unsigned)((l & 7) << 4))));
    }
#pragma unroll
    for (int t = 0; t < 6; ++t)
#pragma unroll
      for (int nt = 0; nt < 4; ++nt)
        acc6[t][nt] = __builtin_amdgcn_mfma_f32_16x16x32_bf16(acur[t], bfrag[nt], acc6[t][nt], 0, 0, 0);
    if (ks < 7) {
#pragma unroll
      for (int t = 0; t < 6; ++t) acur[t] = anxt[t];
    }
  }
  // affine + bias fold
#pragma unroll
  for (int t = 0; t < 6; ++t) {
    const int ob = (t >> 1) * 256 + 32 * w + 16 * (t & 1);
    const f32x4 rs4 = *reinterpret_cast<const f32x4*>(rowsum + ob + lg * 4);
    const f32x4 bq4 = *reinterpret_cast<const f32x4*>(bqkv   + ob + lg * 4);
#pragma unroll
    for (int nt = 0; nt < 4; ++nt)
#pragma unroll
      for (int reg = 0; reg < 4; ++reg)
        acc6[t][nt][reg] = pg4[nt] * acc6[t][nt][reg] + pb4[nt] * rs4[reg] + bq4[reg];
  }
  // folded L2-norm over d for q (t=0,1) and k (t=2,3)
#pragma unroll
  for (int sec = 0; sec < 2; ++sec)
#pragma unroll
    for (int nt = 0; nt < 4; ++nt) {
      float ss = 0.f;
#pragma unroll
      for (int sub = 0; sub < 2; ++sub)
#pragma unroll
        for (int reg = 0; reg < 4; ++reg) {
          const float v = acc6[2 * sec + sub][nt][reg];
          ss += v * v;
        }
      ss += __shfl_xor(ss, 16);
      ss += __shfl_xor(ss, 32);
      const float inv = 1.f / fmaxf(sqrtf(ss), 1e-12f);
#pragma unroll
      for (int sub = 0; sub < 2; ++sub)
#pragma unroll
        for (int reg = 0; reg < 4; ++reg)
          acc6[2 * sec + sub][nt][reg] *= inv;
    }

  // ---------- phase 4: wave-local attention (S^T form, P stays in regs) -------
  const unsigned scr = LDS_SCR + (unsigned)w * 4608u;
  // q/k fragments in-register: shared slot->d bijection kappa(lg,i)=16*(i>>2)+4lg+(i&3)
  bf16x8 qfrag[4], kfrag[4];
#pragma unroll
  for (int nt = 0; nt < 4; ++nt) {
    bf16x8 qv, kv;
#pragma unroll
    for (int sub = 0; sub < 2; ++sub)
#pragma unroll
      for (int reg = 0; reg < 4; ++reg) {
        qv[sub * 4 + reg] = (__bf16)acc6[sub][nt][reg];
        kv[sub * 4 + reg] = (__bf16)acc6[2 + sub][nt][reg];
      }
    qfrag[nt] = qv; kfrag[nt] = kv;
  }
  // vT -> own SCR [d][144B], columns permuted so ds_read slots match kappa above:
  // value v[d][m=nt*16+lm] stored at col p = (nt>>1)*32 + (lm>>2)*8 + (nt&1)*4 + (lm&3)
#pragma unroll
  for (int sub = 0; sub < 2; ++sub)
#pragma unroll
    for (int reg = 0; reg < 4; ++reg) {
      const int d = 16 * sub + 4 * lg + reg;
#pragma unroll
      for (int nt = 0; nt < 4; ++nt) {
        const int pcol = (nt >> 1) * 32 + (lm >> 2) * 8 + (nt & 1) * 4 + (lm & 3);
        *(unsigned short*)(sh + scr + (unsigned)(d * 144 + 2 * pcol)) =
            f2bf(acc6[4 + sub][nt][reg]);
      }
    }
  LDS_FENCE();                                     // RAW: vT writes -> vf reads
  bf16x8 vf[2][2];
#pragma unroll
  for (int ks = 0; ks < 2; ++ks)
#pragma unroll
    for (int mtd = 0; mtd < 2; ++mtd)
      vf[ks][mtd] = *reinterpret_cast<const bf16x8*>(
          sh + scr + (unsigned)((mtd * 16 + lm) * 144 + ks * 64 + lg * 16));
  LDS_FENCE();                                     // WAR: vf reads -> AO writes later

  const float* bh = biasg + w * 4096;              // bias[h][l][m]
  f32x4 oaccT[2][4];
#pragma unroll
  for (int mtd = 0; mtd < 2; ++mtd)
#pragma unroll
    for (int nt = 0; nt < 4; ++nt) oaccT[mtd][nt] = f32x4{0.f, 0.f, 0.f, 0.f};
#pragma unroll
  for (int nt = 0; nt < 4; ++nt) {
    // bias for columns l = nt*16+lm, rows m = mt*16+4lg+reg (f32x4 over reg)
    f32x4 bb[4];
#pragma unroll
    for (int mt = 0; mt < 4; ++mt)
      bb[mt] = *reinterpret_cast<const f32x4*>(bh + (nt * 16 + lm) * 64 + mt * 16 + 4 * lg);
    // S^T tile column-block nt: rows m via (mt,lg,reg), col l via lm
    f32x4 st[4];
#pragma unroll
    for (int mt = 0; mt < 4; ++mt)
      st[mt] = __builtin_amdgcn_mfma_f32_16x16x32_bf16(kfrag[mt], qfrag[nt],
                                                       f32x4{0.f,0.f,0.f,0.f}, 0, 0, 0);
    // softmax over m: 16 in-lane + lg cross-lane (shfl 16,32)
    float mmax = -1e30f;
#pragma unroll
    for (int mt = 0; mt < 4; ++mt)
#pragma unroll
      for (int reg = 0; reg < 4; ++reg) {
        st[mt][reg] += bb[mt][reg];
        mmax = fmaxf(mmax, st[mt][reg]);
      }
    mmax = fmaxf(mmax, __shfl_xor(mmax, 16));
    mmax = fmaxf(mmax, __shfl_xor(mmax, 32));
    float sum = 0.f;
#pragma unroll
    for (int mt = 0; mt < 4; ++mt)
#pragma unroll
      for (int reg = 0; reg < 4; ++reg) {
        const float e = __expf(st[mt][reg] - mmax);
        st[mt][reg] = e;
        sum += e;
      }
    sum += __shfl_xor(sum, 16);
    sum += __shfl_xor(sum, 32);
    const float rinv = 1.f / sum;
    // PV: pf slot i=4sub+reg <- P[m=ks*32+16sub+4lg+reg][l]*rinv (matches vf's kappa)
#pragma unroll
    for (int ks = 0; ks < 2; ++ks) {
      bf16x8 pf;
#pragma unroll
      for (int sub = 0; sub < 2; ++sub)
#pragma unroll
        for (int reg = 0; reg < 4; ++reg)
          pf[sub * 4 + reg] = (__bf16)(st[2 * ks + sub][reg] * rinv);
#pragma unroll
      for (int mtd = 0; mtd < 2; ++mtd)
        oaccT[mtd][nt] = __builtin_amdgcn_mfma_f32_16x16x32_bf16(vf[ks][mtd], pf,
                                                                 oaccT[mtd][nt], 0, 0, 0);
    }
  }
  // AO -> own SCR [l][64B] rows (true-d columns; overwrites vT, vf long consumed)
#pragma unroll
  for (int mtd = 0; mtd < 2; ++mtd)
#pragma unroll
    for (int reg = 0; reg < 4; ++reg) {
      const int d = mtd * 16 + 4 * lg + reg;
#pragma unroll
      for (int nt = 0; nt < 4; ++nt)
        *(unsigned short*)(sh + scr + (unsigned)((nt * 16 + lm) * 64 + 2 * d)) =
            f2bf(oaccT[mtd][nt][reg]);
    }

  // prefetch proj A (global; hidden under the barrier)
  const unsigned char* wpb = (const unsigned char*)wp;
  size_t poff[2];
  bf16x8 pcur[2];
#pragma unroll
  for (int mt = 0; mt < 2; ++mt) {
    poff[mt] = (size_t)(w * 32 + mt * 16 + lm) * 512 + lg * 16;
    pcur[mt] = *reinterpret_cast<const bf16x8*>(wpb + poff[mt]);
  }
  __syncthreads();   // all AO slots visible block-wide

  // ---------- phase 5: proj GEMM + residual (XN+ST) + post-LN + direct store --
  {
    float pog4[4], pob4[4];
#pragma unroll
    for (int nt = 0; nt < 4; ++nt) { pog4[nt] = postg[nt * 16 + lm]; pob4[nt] = postb[nt * 16 + lm]; }
    f32x4 pacc[2][4];
#pragma unroll
    for (int i = 0; i < 2; ++i)
#pragma unroll
      for (int j = 0; j < 4; ++j) pacc[i][j] = f32x4{0.f, 0.f, 0.f, 0.f};
#pragma unroll
    for (int ks = 0; ks < 8; ++ks) {
      bf16x8 pnxt[2];
      if (ks < 7) {
#pragma unroll
        for (int mt = 0; mt < 2; ++mt)
          pnxt[mt] = *reinterpret_cast<const bf16x8*>(wpb + poff[mt] + (ks + 1) * 64);
      }
      bf16x8 bfr[4];
#pragma unroll
      for (int nt = 0; nt < 4; ++nt)
        bfr[nt] = *reinterpret_cast<const bf16x8*>(
            sh + LDS_SCR + (unsigned)(ks * 4608 + (nt * 16 + lm) * 64 + lg * 16));
#pragma unroll
      for (int mt = 0; mt < 2; ++mt)
#pragma unroll
        for (int nt = 0; nt < 4; ++nt)
          pacc[mt][nt] = __builtin_amdgcn_mfma_f32_16x16x32_bf16(pcur[mt], bfr[nt], pacc[mt][nt], 0, 0, 0);
      if (ks < 7) {
#pragma unroll
        for (int mt = 0; mt < 2; ++mt) pcur[mt] = pnxt[mt];
      }
    }
#pragma unroll
    for (int mt = 0; mt < 2; ++mt) {
      const float4 bp4 = *reinterpret_cast<const float4*>(bproj + w * 32 + mt * 16 + lg * 4);
#pragma unroll
      for (int reg = 0; reg < 4; ++reg) {
        const int c = w * 32 + mt * 16 + lg * 4 + reg;
        const float bp = ((const float*)&bp4)[reg];
        const float2 ms = *reinterpret_cast<const float2*>(sh + LDS_ST + c * 8);
        float y[4];
        float s1 = 0.f, s2 = 0.f;
#pragma unroll
        for (int nt = 0; nt < 4; ++nt) {
          const int l = nt * 16 + lm;
          const float xh = bf2f(*(const unsigned short*)(
              sh + LDS_XN + l * 512 + (((unsigned)(2 * c)) ^ ((unsigned)((l & 7) << 4)))));
          const float v = xh * ms.y + ms.x + pacc[mt][nt][reg] + bp;
          y[nt] = v;
          s1 += v; s2 += v * v;
        }
        s1 += __shfl_xor(s1, 1); s2 += __shfl_xor(s2, 1);
        s1 += __shfl_xor(s1, 2); s2 += __shfl_xor(s2, 2);
        s1 += __shfl_xor(s1, 4); s2 += __shfl_xor(s2, 4);
        s1 += __shfl_xor(s1, 8); s2 += __shfl_xor(s2, 8);
        const float mean = s1 * (1.f / 64.f);
        const float var  = s2 * (1.f / 64.f) - mean * mean;
        const float rstd = rsqrtf(fmaxf(var, 0.f) + 1e-5f);
        float* orow = out + (size_t)b * 16384 + (size_t)c * 64;
#pragma unroll
        for (int nt = 0; nt < 4; ++nt) {
          const float v = y[nt];
          orow[nt * 16 + lm] = v + (v - mean) * rstd * pog4[nt] + pob4[nt];
        }
      }
    }
  }
}

extern "C" void kernel_launch(void* const* d_in, const int* in_sizes, int n_in,
                              void* d_out, int out_size, void* d_ws, size_t ws_size,
                              hipStream_t stream) {
  const float* X     = (const float*)d_in[0];
  const float* preg  = (const float*)d_in[1];
  const float* preb  = (const float*)d_in[2];
  const float* postg = (const float*)d_in[3];
  const float* postb = (const float*)d_in[4];
  const float* Wqkv  = (const float*)d_in[5];
  const float* bqkv  = (const float*)d_in[6];
  const float* Wproj = (const float*)d_in[7];
  const float* bproj = (const float*)d_in[8];
  const float* table = (const float*)d_in[9];

  unsigned short* wq = (unsigned short*)d_ws;                    // 768*256 bf16
  unsigned short* wp = (unsigned short*)((char*)d_ws + 393216);  // 256*256 bf16
  float* biasg       = (float*)((char*)d_ws + 524288);           // 8*64*64 f32
  float* rowsum      = (float*)((char*)d_ws + 655360);           // 768 f32

  prep_kernel<<<768, 256, 0, stream>>>(Wqkv, Wproj, table, wq, wp, biasg, rowsum);
  win_attn_kernel<<<2048, 512, 0, stream>>>(X, preg, preb, postg, postb,
                                            bqkv, bproj, wq, wp, biasg, rowsum,
                                            (float*)d_out);
}